// Round 2
// baseline (1818.926 us; speedup 1.0000x reference)
//
#include <hip/hip_runtime.h>
#include <math.h>

#define B_    256
#define T_    512
#define TH    514          // T + 2 halo rows
#define CP    320          // padded channel stride (both Cin and Cout)
#define COUT  320
#define NSUBJ 4
#define XPAD  36           // LDS row stride in u16: 72B = 18 banks, gcd(18,32)=2 -> conflict-free b128
#define OPAD  72           // out-tile LDS row stride in u16 (144B, 16B-aligned)

typedef unsigned int u32;
typedef unsigned short u16;

typedef __bf16 bf16x8 __attribute__((ext_vector_type(8)));
typedef float  f32x16 __attribute__((ext_vector_type(16)));

union FragU { uint4 u4; bf16x8 v; };

__device__ __forceinline__ float bf2f(u16 u) {
    union { u32 i; float f; } v; v.i = ((u32)u) << 16; return v.f;
}
__device__ __forceinline__ u16 f2bf(float f) {
    union { float ff; u32 i; } v; v.ff = f;
    u32 x = v.i;
    x += 0x7fffu + ((x >> 16) & 1u);   // RNE
    return (u16)(x >> 16);
}
__device__ __forceinline__ float2 bfp2(u32 u) {
    float2 r;
    r.x = bf2f((u16)(u & 0xffffu));
    r.y = bf2f((u16)(u >> 16));
    return r;
}
__device__ __forceinline__ float gelu_exact(float x) {
    return 0.5f * x * (1.0f + erff(x * 0.70710678118654752440f));
}
__device__ __forceinline__ bf16x8 ldfrag(const u16* p) {
    FragU f; f.u4 = *(const uint4*)p; return f.v;
}

// ---------------------------------------------------------------------------
// prep_w: fp32 [co][Cin][3] -> bf16 [tap][co][CP] (ci >= Cin zeroed)
// ---------------------------------------------------------------------------
__global__ void prep_w(const float* __restrict__ w, u16* __restrict__ wb, int Cin) {
    const int idx = blockIdx.x * 256 + threadIdx.x;
    if (idx >= 3 * CP * CP) return;
    const int tap = idx / (CP * CP);
    const int r   = idx - tap * CP * CP;
    const int co  = r / CP;
    const int ci  = r - co * CP;
    const float v = (ci < Cin) ? w[((size_t)co * Cin + ci) * 3 + tap] : 0.f;
    wb[idx] = f2bf(v);
}

// zero halo rows (t=-1 and t=T) of the act buffer [B][TH][CP]
__global__ void zero_halo(u16* __restrict__ xh) {
    const int idx = blockIdx.x * 256 + threadIdx.x;   // 20480 uint4 total
    const int i8 = idx * 8;
    const int b = i8 / (2 * CP);
    const int r = i8 - b * 2 * CP;
    const int row = (r < CP) ? 0 : (TH - 1);
    const int c   = (r < CP) ? r : r - CP;
    *(uint4*)(xh + ((size_t)b * TH + row) * CP + c) = make_uint4(0u, 0u, 0u, 0u);
}

// zero the BN partial-sum buffers (p1,p2 contiguous: 2*B_*COUT floats)
__global__ void zero_p(float4* __restrict__ p) {
    p[(size_t)blockIdx.x * 256 + threadIdx.x] = make_float4(0.f, 0.f, 0.f, 0.f);
}

// prep_x: X fp32 [b][271][512] -> act bf16 [b][1+t][ci] (ci>=271 zero)
__global__ __launch_bounds__(256) void prep_x(
    const float* __restrict__ X, u16* __restrict__ xh) {
    __shared__ float Lt[64][65];
    const int t0 = blockIdx.x * 64, c0 = blockIdx.y * 64, b = blockIdx.z;
    {
        const int cr = threadIdx.x >> 2, tq = (threadIdx.x & 3) * 16;
        if (c0 + cr < 271) {
            const float* xp = X + ((size_t)b * 271 + c0 + cr) * 512 + t0 + tq;
            #pragma unroll
            for (int k = 0; k < 16; k += 4) {
                const float4 v = *(const float4*)(xp + k);
                Lt[cr][tq + k]     = v.x;
                Lt[cr][tq + k + 1] = v.y;
                Lt[cr][tq + k + 2] = v.z;
                Lt[cr][tq + k + 3] = v.w;
            }
        } else {
            #pragma unroll
            for (int k = 0; k < 16; ++k) Lt[cr][tq + k] = 0.f;
        }
    }
    __syncthreads();
    {
        const int tr = threadIdx.x >> 2, cq = (threadIdx.x & 3) * 16;
        u16 tmp[16];
        #pragma unroll
        for (int k = 0; k < 16; ++k) tmp[k] = f2bf(Lt[cq + k][tr]);
        u16* op = xh + ((size_t)b * TH + 1 + t0 + tr) * CP + c0 + cq;
        *(uint4*)op       = *(const uint4*)&tmp[0];
        *(uint4*)(op + 8) = *(const uint4*)&tmp[8];
    }
}

// ---------------------------------------------------------------------------
// Implicit-GEMM conv1d (K=3 SAME) via mfma_f32_32x32x16_bf16.
// 512 thr / 8 waves; block tile M=256 t x N=64 co; wave tile 64 t x 32 co.
// Double-buffered LDS (2 x 32.4 KB), one barrier per 32-ci chunk:
//   loadChunk(ch+1) -> compute(buf cur) -> storeChunk(buf cur^1) -> barrier.
// vmcnt drain for the staged loads lands AFTER the MFMA section (T3/T14).
// Epilogue: bias + residual + BN stats, out-tile repacked through LDS so
// global stores are fully-coalesced dwordx4 (full 128B lines per instr).
// Grid: 2560 blocks, chunked-XCD swizzled (all 10 blocks of one b -> 1 XCD).
// ---------------------------------------------------------------------------
template<int HAS_RES>
__global__ __launch_bounds__(512, 4) void conv_mfma(
    const u16* __restrict__ xh,
    const u16* __restrict__ wb,
    const float* __restrict__ bias,
    const u16* __restrict__ res,     // halo layout [B][TH][CP] (conv input)
    u16* __restrict__ outp,          // bf16 [B][T][CP] pre-BN y
    float* __restrict__ p1,
    float* __restrict__ p2)
{
    __shared__ u16 Xs[2][258][XPAD];      // 37,152 B
    __shared__ u16 Ws[2][3][64][XPAD];    // 27,648 B

    const int tid = threadIdx.x;
    // chunked XCD swizzle: 2560 = 8 * 320, bijective
    const u32 bid = blockIdx.x;
    const u32 lin = (bid & 7u) * 320u + (bid >> 3);
    const int b   = (int)(lin / 10u);
    const int r10 = (int)(lin - (u32)b * 10u);
    const int co0 = (r10 >> 1) * 64;
    const int t0  = (r10 & 1) * 256;

    const int lane = tid & 63;
    const int wv   = tid >> 6;       // 0..7
    const int wr   = wv >> 1;        // 0..3: m-offset wr*64
    const int wc   = wv & 1;         // 0..1: n-offset wc*32
    const int l31  = lane & 31;
    const int kb8  = (lane >> 5) * 8;
    const int rofs = (lane >> 5) * 4;

    f32x16 acc[2];
    #pragma unroll
    for (int mi = 0; mi < 2; ++mi)
        #pragma unroll
        for (int r = 0; r < 16; ++r) acc[mi][r] = 0.f;

    const u16* xbase = xh + ((size_t)b * TH + t0) * CP;   // local row 0 = Xh row t0

    // X staging: rows 0..255 by i = tid (row=i>>2, q=i&3) and i=tid+512; tail
    // rows 256..257 (8 uint4) by tid<8. W staging: j=tid (tap 0/1), j=tid+512
    // (tap 2, tid<256).
    const int xr0 = tid >> 2, xq = (tid & 3) * 8;
    uint4 xg0, xg1, xgt, wg0, wg1;

    auto loadChunk = [&](int ci0) {
        xg0 = *(const uint4*)(xbase + (size_t)xr0 * CP + ci0 + xq);
        xg1 = *(const uint4*)(xbase + (size_t)(xr0 + 128) * CP + ci0 + xq);
        if (tid < 8)
            xgt = *(const uint4*)(xbase + (size_t)(256 + (tid >> 2)) * CP + ci0 + (tid & 3) * 8);
        {
            const int tap = tid >> 8, co = (tid & 255) >> 2, q = tid & 3;
            wg0 = *(const uint4*)(wb + ((size_t)tap * CP + co0 + co) * CP + ci0 + q * 8);
        }
        if (tid < 256)
            wg1 = *(const uint4*)(wb + ((size_t)2 * CP + co0 + (tid >> 2)) * CP + ci0 + (tid & 3) * 8);
    };
    auto storeChunk = [&](int buf) {
        *(uint4*)&Xs[buf][xr0][xq]       = xg0;
        *(uint4*)&Xs[buf][xr0 + 128][xq] = xg1;
        if (tid < 8)
            *(uint4*)&Xs[buf][256 + (tid >> 2)][(tid & 3) * 8] = xgt;
        {
            const int tap = tid >> 8, co = (tid & 255) >> 2, q = tid & 3;
            *(uint4*)&Ws[buf][tap][co][q * 8] = wg0;
        }
        if (tid < 256)
            *(uint4*)&Ws[buf][2][tid >> 2][(tid & 3) * 8] = wg1;
    };
    auto compute = [&](int buf) {
        #pragma unroll
        for (int ks = 0; ks < 2; ++ks) {
            #pragma unroll
            for (int tap = 0; tap < 3; ++tap) {
                const bf16x8 bw = ldfrag(&Ws[buf][tap][wc * 32 + l31][ks * 16 + kb8]);
                #pragma unroll
                for (int mi = 0; mi < 2; ++mi) {
                    const bf16x8 av = ldfrag(&Xs[buf][wr * 64 + mi * 32 + l31 + tap][ks * 16 + kb8]);
                    acc[mi] = __builtin_amdgcn_mfma_f32_32x32x16_bf16(av, bw, acc[mi], 0, 0, 0);
                }
            }
        }
    };

    loadChunk(0);
    storeChunk(0);
    __syncthreads();
    for (int ch = 0; ch < 10; ++ch) {
        const int cur = ch & 1;
        if (ch < 9) loadChunk((ch + 1) * 32);
        compute(cur);
        if (ch < 9) storeChunk(cur ^ 1);
        __syncthreads();
    }

    // ---- fused epilogue: bias + residual + BN stats + packed bf16 store
    u16*   outLds = (u16*)&Xs[0][0][0];        // [256][OPAD] = 36,864 B (fits Xs)
    float* red    = (float*)&Ws[0][0][0][0];   // 4 KB (fits Ws)

    const int wslot = wr * 2 + (lane >> 5);    // 0..7
    const int co = co0 + wc * 32 + l31;
    const float bv = bias[co];
    float s1 = 0.f, s2 = 0.f;
    #pragma unroll
    for (int mi = 0; mi < 2; ++mi) {
        #pragma unroll
        for (int r = 0; r < 16; ++r) {
            const int tl = wr * 64 + mi * 32 + (r & 3) + 8 * (r >> 2) + rofs;
            float v = acc[mi][r] + bv;
            if (HAS_RES) v += bf2f(res[((size_t)b * TH + t0 + tl + 1) * CP + co]);
            const u16 h = f2bf(v);
            const float vq = bf2f(h);          // stats on the rounded value we store
            s1 += vq;
            s2 = fmaf(vq, vq, s2);
            outLds[tl * OPAD + wc * 32 + l31] = h;
        }
    }
    red[((wc * 2 + 0) * 8 + wslot) * 32 + l31] = s1;
    red[((wc * 2 + 1) * 8 + wslot) * 32 + l31] = s2;
    __syncthreads();

    // packed, fully-coalesced stores: 4 x dwordx4 per thread
    #pragma unroll
    for (int s = 0; s < 4; ++s) {
        const int i = tid + s * 512;
        const int row = i >> 3, q = i & 7;
        const uint4 val = *(const uint4*)&outLds[row * OPAD + q * 8];
        *(uint4*)(outp + ((size_t)b * T_ + t0 + row) * CP + co0 + q * 8) = val;
    }
    if (tid < 128) {
        const int j = tid >> 6, c = tid & 63;
        const int wcc = c >> 5, cc = c & 31;
        float s = 0.f;
        #pragma unroll
        for (int w = 0; w < 8; ++w) s += red[((wcc * 2 + j) * 8 + w) * 32 + cc];
        float* dst = j ? p2 : p1;
        atomicAdd(&dst[(size_t)b * COUT + co0 + c], s);
    }
}

// ---------------------------------------------------------------------------
// finalize: reduce per-b partials per subject -> scale/shift
// ---------------------------------------------------------------------------
__global__ void finalize_kernel(
    const float* __restrict__ p1, const float* __restrict__ p2,
    const int* __restrict__ subj,
    const float* __restrict__ gamma, const float* __restrict__ beta,
    float* __restrict__ scale, float* __restrict__ shift)
{
    const int idx = blockIdx.x * blockDim.x + threadIdx.x;
    if (idx >= NSUBJ * COUT) return;
    const int s = idx / COUT;
    const int c = idx - s * COUT;
    float s1 = 0.f, s2 = 0.f; int nb = 0;
    for (int b = 0; b < B_; ++b) {
        if (subj[b] == s) {
            s1 += p1[(size_t)b * COUT + c];
            s2 += p2[(size_t)b * COUT + c];
            ++nb;
        }
    }
    const float cnt  = fmaxf((float)nb * (float)T_, 1.0f);
    const float mean = s1 / cnt;
    const float var  = s2 / cnt - mean * mean;
    const float sc = gamma[idx] * (1.0f / sqrtf(var + 1e-5f));
    scale[idx] = sc;
    shift[idx] = beta[idx] - mean * sc;
}

// BN+GELU: y bf16 plain [b][t][c] -> act bf16 halo layout [b][1+t][c]
__global__ __launch_bounds__(256) void bn_gelu_b2b(
    const u16* __restrict__ x, const int* __restrict__ subj,
    const float* __restrict__ scale, const float* __restrict__ shift,
    u16* __restrict__ out)
{
    const u32 base = ((u32)blockIdx.x * 256u + (u32)threadIdx.x) * 8u;
    const u32 b = base / ((u32)T_ * CP);
    const u32 r = base - b * ((u32)T_ * CP);
    const u32 t = r / CP;
    const u32 c = r - t * CP;
    const int s = subj[b];
    const uint4 u = *(const uint4*)(x + base);
    const float* scp = scale + (size_t)s * COUT + c;
    const float* shp = shift + (size_t)s * COUT + c;
    const float4 sca = *(const float4*)(scp);
    const float4 scb = *(const float4*)(scp + 4);
    const float4 sha = *(const float4*)(shp);
    const float4 shb = *(const float4*)(shp + 4);
    const float scv[8] = {sca.x, sca.y, sca.z, sca.w, scb.x, scb.y, scb.z, scb.w};
    const float shv[8] = {sha.x, sha.y, sha.z, sha.w, shb.x, shb.y, shb.z, shb.w};
    const u32 w[4] = {u.x, u.y, u.z, u.w};
    u16 o[8];
    #pragma unroll
    for (int k = 0; k < 4; ++k) {
        const float2 f = bfp2(w[k]);
        o[2 * k]     = f2bf(gelu_exact(f.x * scv[2 * k]     + shv[2 * k]));
        o[2 * k + 1] = f2bf(gelu_exact(f.y * scv[2 * k + 1] + shv[2 * k + 1]));
    }
    u16* op = out + ((size_t)b * TH + 1 + t) * CP + c;
    *(uint4*)op = *(const uint4*)o;
}

// final: BN+GELU + transpose [b][t][c] bf16 plain -> [b][c][t] fp32 (d_out)
__global__ __launch_bounds__(256) void final_tr(
    const u16* __restrict__ x, const int* __restrict__ subj,
    const float* __restrict__ scale, const float* __restrict__ shift,
    float* __restrict__ out)
{
    __shared__ float Lt[64][65];
    const int t0 = blockIdx.x * 64, c0 = blockIdx.y * 64, b = blockIdx.z;
    const int s = subj[b];
    {
        const int tt = threadIdx.x >> 2, chs = (threadIdx.x & 3) * 16;
        const u16* xp = x + ((size_t)b * T_ + t0 + tt) * COUT + c0 + chs;
        const uint4 u0 = *(const uint4*)xp;
        const uint4 u1 = *(const uint4*)(xp + 8);
        const u32 wd[8] = {u0.x, u0.y, u0.z, u0.w, u1.x, u1.y, u1.z, u1.w};
        const float* scp = scale + (size_t)s * COUT + c0 + chs;
        const float* shp = shift + (size_t)s * COUT + c0 + chs;
        #pragma unroll
        for (int k = 0; k < 8; ++k) {
            const float2 f = bfp2(wd[k]);
            Lt[tt][chs + 2 * k]     = gelu_exact(f.x * scp[2 * k]     + shp[2 * k]);
            Lt[tt][chs + 2 * k + 1] = gelu_exact(f.y * scp[2 * k + 1] + shp[2 * k + 1]);
        }
    }
    __syncthreads();
    {
        const int cr = threadIdx.x >> 2, tch = (threadIdx.x & 3) * 16;
        float* op = out + ((size_t)b * COUT + c0 + cr) * T_ + t0 + tch;
        #pragma unroll
        for (int k = 0; k < 16; k += 4)
            *(float4*)(op + k) = make_float4(Lt[tch + k][cr], Lt[tch + k + 1][cr],
                                             Lt[tch + k + 2][cr], Lt[tch + k + 3][cr]);
    }
}

// ---------------------------------------------------------------------------

extern "C" void kernel_launch(void* const* d_in, const int* in_sizes, int n_in,
                              void* d_out, int out_size, void* d_ws, size_t ws_size,
                              hipStream_t stream) {
    const float* X    = (const float*)d_in[0];
    const int*   subj = (const int*)d_in[1];
    const float* w0   = (const float*)d_in[2];
    const float* b0   = (const float*)d_in[3];
    const float* w1   = (const float*)d_in[4];
    const float* b1   = (const float*)d_in[5];
    const float* w2   = (const float*)d_in[6];
    const float* b2   = (const float*)d_in[7];
    const float* g0   = (const float*)d_in[8];
    const float* be0  = (const float*)d_in[9];
    const float* g1   = (const float*)d_in[10];
    const float* be1  = (const float*)d_in[11];
    const float* g2   = (const float*)d_in[12];
    const float* be2  = (const float*)d_in[13];

    // ws layout (identical footprint to previous version)
    const size_t actElems = (size_t)B_ * TH * CP;      // 42,106,880  (84.21 MB)
    const size_t yElems   = (size_t)B_ * T_ * CP;      // 41,943,040  (83.89 MB)
    u16* act  = (u16*)d_ws;
    u16* y    = act + actElems;
    u16* wb0  = y + yElems;
    u16* wb1  = wb0 + 3 * CP * CP;
    u16* wb2  = wb1 + 3 * CP * CP;
    float* p1 = (float*)(wb2 + 3 * CP * CP);           // [B_][COUT]
    float* p2 = p1 + (size_t)B_ * COUT;                // [B_][COUT]
    float* sc = p2 + (size_t)B_ * COUT;
    float* sh = sc + NSUBJ * COUT;

    const dim3 cgrid(2560);                // conv: 2 t-tiles x 5 co-tiles x 256 b (swizzled 1-D)
    const dim3 pgrid(8, 5, B_);            // prep_x / final_tr tiles
    const int  agrid = (int)(((size_t)B_ * T_ * CP) / 8 / 256);   // 20480
    const int  wgrid = (3 * CP * CP + 255) / 256;                 // 1200
    const int  zgrid = (2 * B_ * COUT) / 4 / 256;                 // 160

    // ---- preparation
    prep_w<<<wgrid, 256, 0, stream>>>(w0, wb0, 271);
    prep_w<<<wgrid, 256, 0, stream>>>(w1, wb1, 320);
    prep_w<<<wgrid, 256, 0, stream>>>(w2, wb2, 320);
    zero_halo<<<80, 256, 0, stream>>>(act);
    prep_x<<<pgrid, 256, 0, stream>>>(X, act);

    // ---- layer 0
    zero_p<<<zgrid, 256, 0, stream>>>((float4*)p1);
    conv_mfma<0><<<cgrid, 512, 0, stream>>>(act, wb0, b0, act, y, p1, p2);
    finalize_kernel<<<5, 256, 0, stream>>>(p1, p2, subj, g0, be0, sc, sh);
    bn_gelu_b2b<<<agrid, 256, 0, stream>>>(y, subj, sc, sh, act);

    // ---- layer 1 (residual)
    zero_p<<<zgrid, 256, 0, stream>>>((float4*)p1);
    conv_mfma<1><<<cgrid, 512, 0, stream>>>(act, wb1, b1, act, y, p1, p2);
    finalize_kernel<<<5, 256, 0, stream>>>(p1, p2, subj, g1, be1, sc, sh);
    bn_gelu_b2b<<<agrid, 256, 0, stream>>>(y, subj, sc, sh, act);

    // ---- layer 2 (residual)
    zero_p<<<zgrid, 256, 0, stream>>>((float4*)p1);
    conv_mfma<1><<<cgrid, 512, 0, stream>>>(act, wb2, b2, act, y, p1, p2);
    finalize_kernel<<<5, 256, 0, stream>>>(p1, p2, subj, g2, be2, sc, sh);
    final_tr<<<pgrid, 256, 0, stream>>>(y, subj, sc, sh, (float*)d_out);
}

// Round 3
// 1270.752 us; speedup vs baseline: 1.4314x; 1.4314x over previous
//
#include <hip/hip_runtime.h>
#include <math.h>

#define B_    256
#define T_    512
#define TH    514          // T + 2 halo rows
#define CP    320          // padded channel stride (both Cin and Cout)
#define COUT  320
#define NSUBJ 4

typedef unsigned int u32;
typedef unsigned short u16;

typedef __bf16 bf16x8 __attribute__((ext_vector_type(8)));
typedef float  f32x16 __attribute__((ext_vector_type(16)));

union FragU { uint4 u4; bf16x8 v; };

__device__ __forceinline__ float bf2f(u16 u) {
    union { u32 i; float f; } v; v.i = ((u32)u) << 16; return v.f;
}
__device__ __forceinline__ u16 f2bf(float f) {
    union { float ff; u32 i; } v; v.ff = f;
    u32 x = v.i;
    x += 0x7fffu + ((x >> 16) & 1u);   // RNE
    return (u16)(x >> 16);
}
__device__ __forceinline__ float2 bfp2(u32 u) {
    float2 r;
    r.x = bf2f((u16)(u & 0xffffu));
    r.y = bf2f((u16)(u >> 16));
    return r;
}
__device__ __forceinline__ float gelu_exact(float x) {
    return 0.5f * x * (1.0f + erff(x * 0.70710678118654752440f));
}
__device__ __forceinline__ bf16x8 ldfrag(const u16* p) {
    FragU f; f.u4 = *(const uint4*)p; return f.v;
}
// async global->LDS, 16B per lane; LDS dest is wave-uniform base + lane*16
__device__ __forceinline__ void gload16(const u16* g, u16* l) {
    __builtin_amdgcn_global_load_lds(
        (const __attribute__((address_space(1))) u32*)(const void*)g,
        (__attribute__((address_space(3))) u32*)(void*)l, 16, 0, 0);
}

// ---------------------------------------------------------------------------
// prep_w: fp32 [co][Cin][3] -> bf16 [tap][co][CP] (ci >= Cin zeroed)
// ---------------------------------------------------------------------------
__global__ void prep_w(const float* __restrict__ w, u16* __restrict__ wb, int Cin) {
    const int idx = blockIdx.x * 256 + threadIdx.x;
    if (idx >= 3 * CP * CP) return;
    const int tap = idx / (CP * CP);
    const int r   = idx - tap * CP * CP;
    const int co  = r / CP;
    const int ci  = r - co * CP;
    const float v = (ci < Cin) ? w[((size_t)co * Cin + ci) * 3 + tap] : 0.f;
    wb[idx] = f2bf(v);
}

// zero halo rows (t=-1 and t=T) of the act buffer [B][TH][CP]
__global__ void zero_halo(u16* __restrict__ xh) {
    const int idx = blockIdx.x * 256 + threadIdx.x;   // 20480 uint4 total
    const int i8 = idx * 8;
    const int b = i8 / (2 * CP);
    const int r = i8 - b * 2 * CP;
    const int row = (r < CP) ? 0 : (TH - 1);
    const int c   = (r < CP) ? r : r - CP;
    *(uint4*)(xh + ((size_t)b * TH + row) * CP + c) = make_uint4(0u, 0u, 0u, 0u);
}

// zero the BN partial-sum buffers (p1,p2 contiguous: 2*B_*COUT floats)
__global__ void zero_p(float4* __restrict__ p) {
    p[(size_t)blockIdx.x * 256 + threadIdx.x] = make_float4(0.f, 0.f, 0.f, 0.f);
}

// prep_x: X fp32 [b][271][512] -> act bf16 [b][1+t][ci] (ci>=271 zero)
__global__ __launch_bounds__(256) void prep_x(
    const float* __restrict__ X, u16* __restrict__ xh) {
    __shared__ float Lt[64][65];
    const int t0 = blockIdx.x * 64, c0 = blockIdx.y * 64, b = blockIdx.z;
    {
        const int cr = threadIdx.x >> 2, tq = (threadIdx.x & 3) * 16;
        if (c0 + cr < 271) {
            const float* xp = X + ((size_t)b * 271 + c0 + cr) * 512 + t0 + tq;
            #pragma unroll
            for (int k = 0; k < 16; k += 4) {
                const float4 v = *(const float4*)(xp + k);
                Lt[cr][tq + k]     = v.x;
                Lt[cr][tq + k + 1] = v.y;
                Lt[cr][tq + k + 2] = v.z;
                Lt[cr][tq + k + 3] = v.w;
            }
        } else {
            #pragma unroll
            for (int k = 0; k < 16; ++k) Lt[cr][tq + k] = 0.f;
        }
    }
    __syncthreads();
    {
        const int tr = threadIdx.x >> 2, cq = (threadIdx.x & 3) * 16;
        u16 tmp[16];
        #pragma unroll
        for (int k = 0; k < 16; ++k) tmp[k] = f2bf(Lt[cq + k][tr]);
        u16* op = xh + ((size_t)b * TH + 1 + t0 + tr) * CP + c0 + cq;
        *(uint4*)op       = *(const uint4*)&tmp[0];
        *(uint4*)(op + 8) = *(const uint4*)&tmp[8];
    }
}

// ---------------------------------------------------------------------------
// Implicit-GEMM conv1d (K=3 SAME) via mfma_f32_32x32x16_bf16, m97 skeleton.
// 256 thr / 4 waves; block tile M=256 t x N=64 co; wave tile 64 t x 64 co.
// Staging: __builtin_amdgcn_global_load_lds width=16 (no reg round-trip).
// LDS linear [row][32 u16] (64B rows); XOR swizzle on BOTH sides:
//   write: per-lane pre-swizzled GLOBAL source octet q' = (l&3)^((l>>2)&3)
//   read : byte_addr = row*64 + (col_byte ^ ((row&3)<<4))
// -> ds_read_b128 is ~conflict-free (2-way per 8-lane phase = free).
// K-loop: 10 chunks of 32 ci, 2 barriers/chunk; 4 block-contexts/CU overlap.
// Epilogue: bias + residual + BN stats + 2-pass LDS repack -> dwordx4 stores;
// stats atomically added into p1/p2[b][co] (exactly 2 contributors/slot).
// ---------------------------------------------------------------------------
template<int HAS_RES>
__global__ __launch_bounds__(256, 4) void conv_mfma(
    const u16* __restrict__ xh,
    const u16* __restrict__ wb,
    const float* __restrict__ bias,
    const u16* __restrict__ res,     // halo layout [B][TH][CP] (conv input)
    u16* __restrict__ outp,          // bf16 [B][T][CP] pre-BN y
    float* __restrict__ p1,
    float* __restrict__ p2)
{
    __shared__ u16 Xs[272][32];      // 17,408 B (258 used rows + pad to 17 instrs)
    __shared__ u16 Ws[192][32];      // 12,288 B (row = tap*64 + co_local)

    const int tid = threadIdx.x;
    // chunked XCD swizzle: 2560 = 8 * 320, bijective
    const u32 bid = blockIdx.x;
    const u32 lin = (bid & 7u) * 320u + (bid >> 3);
    const int b   = (int)(lin / 10u);
    const int r10 = (int)(lin - (u32)b * 10u);
    const int co0 = (r10 >> 1) * 64;
    const int t0  = (r10 & 1) * 256;

    const int lane = tid & 63;
    const int wv   = tid >> 6;       // 0..3, t-subtile = wv*64
    const int l31  = lane & 31;
    const int hi   = lane >> 5;      // 0/1
    const int kb8  = hi * 8;

    f32x16 acc[2][2];
    #pragma unroll
    for (int mi = 0; mi < 2; ++mi)
        #pragma unroll
        for (int ni = 0; ni < 2; ++ni)
            #pragma unroll
            for (int r = 0; r < 16; ++r) acc[mi][ni][r] = 0.f;

    const u16* xbase = xh + ((size_t)b * TH + t0) * CP;   // local row 0 = halo row t0
    const char* XsB = (const char*)&Xs[0][0];
    const char* WsB = (const char*)&Ws[0][0];

    // per-lane source pre-swizzle: lane l supplies the 8-ci octet that the
    // swizzled read expects at LDS (row=16u+(l>>2), colslot=(l&3))
    const int lrow = lane >> 2;                 // 0..15 within instr
    const int lq   = (lane & 3) ^ (lrow & 3);   // inverse-swizzled ci octet

    auto stageChunk = [&](int ci0) {
        // 17 X-instrs (rows 0..271) + 12 W-instrs, round-robin over 4 waves
        for (int u = wv; u < 29; u += 4) {
            if (u < 17) {
                const int row = u * 16 + lrow;            // local halo row
                gload16(xbase + (size_t)row * CP + ci0 + lq * 8, &Xs[u * 16][0]);
            } else {
                const int j = u - 17;                     // 0..11
                const int r = j * 16 + lrow;              // = tap*64 + co_local
                const int tap = r >> 6, col = r & 63;
                gload16(wb + ((size_t)tap * CP + co0 + col) * CP + ci0 + lq * 8,
                        &Ws[j * 16][0]);
            }
        }
    };

    for (int ch = 0; ch < 10; ++ch) {
        stageChunk(ch * 32);
        __syncthreads();               // implies vmcnt(0): staged data visible
        __builtin_amdgcn_s_setprio(1);
        #pragma unroll
        for (int ks = 0; ks < 2; ++ks) {
            const int cb = (ks * 16 + kb8) * 2;           // 0/16/32/48 bytes
            #pragma unroll
            for (int tap = 0; tap < 3; ++tap) {
                const int rw0 = tap * 64 + l31;
                const int rw1 = rw0 + 32;
                const bf16x8 bw0 = ldfrag((const u16*)(WsB + rw0 * 64 + (cb ^ ((rw0 & 3) << 4))));
                const bf16x8 bw1 = ldfrag((const u16*)(WsB + rw1 * 64 + (cb ^ ((rw1 & 3) << 4))));
                #pragma unroll
                for (int mi = 0; mi < 2; ++mi) {
                    const int ra = wv * 64 + mi * 32 + l31 + tap;
                    const bf16x8 av = ldfrag((const u16*)(XsB + ra * 64 + (cb ^ ((ra & 3) << 4))));
                    acc[mi][0] = __builtin_amdgcn_mfma_f32_32x32x16_bf16(av, bw0, acc[mi][0], 0, 0, 0);
                    acc[mi][1] = __builtin_amdgcn_mfma_f32_32x32x16_bf16(av, bw1, acc[mi][1], 0, 0, 0);
                }
            }
        }
        __builtin_amdgcn_s_setprio(0);
        __syncthreads();               // readers done before next stage overwrites
    }

    // ---- fused epilogue: bias + residual + BN stats + packed bf16 store
    u16*   oT  = (u16*)&Xs[0][0];      // [128][64] u16 = 16 KB (2 passes over t)
    float* red = (float*)&Ws[0][0];    // [2][2][8][32] floats = 4 KB

    const int wslot = wv * 2 + hi;     // 0..7
    float s1[2] = {0.f, 0.f}, s2[2] = {0.f, 0.f};

    #pragma unroll
    for (int p = 0; p < 2; ++p) {
        if ((wv >> 1) == p) {
            #pragma unroll
            for (int ni = 0; ni < 2; ++ni) {
                const int co = co0 + ni * 32 + l31;
                const float bv = bias[co];
                #pragma unroll
                for (int mi = 0; mi < 2; ++mi) {
                    #pragma unroll
                    for (int r = 0; r < 16; ++r) {
                        const int tl = wv * 64 + mi * 32 + (r & 3) + 8 * (r >> 2) + hi * 4;
                        float v = acc[mi][ni][r] + bv;
                        if (HAS_RES) v += bf2f(res[((size_t)b * TH + t0 + tl + 1) * CP + co]);
                        const u16 h = f2bf(v);
                        const float vq = bf2f(h);   // stats on the rounded stored value
                        s1[ni] += vq;
                        s2[ni] = fmaf(vq, vq, s2[ni]);
                        oT[(tl - p * 128) * 64 + ni * 32 + l31] = h;
                    }
                }
            }
        }
        __syncthreads();
        #pragma unroll
        for (int s = 0; s < 4; ++s) {
            const int i = tid + s * 256;
            const int row = i >> 3, q = i & 7;
            *(uint4*)(outp + ((size_t)b * T_ + t0 + p * 128 + row) * CP + co0 + q * 8) =
                *(const uint4*)&oT[row * 64 + q * 8];
        }
        __syncthreads();
    }

    red[((0 * 2 + 0) * 8 + wslot) * 32 + l31] = s1[0];
    red[((0 * 2 + 1) * 8 + wslot) * 32 + l31] = s2[0];
    red[((1 * 2 + 0) * 8 + wslot) * 32 + l31] = s1[1];
    red[((1 * 2 + 1) * 8 + wslot) * 32 + l31] = s2[1];
    __syncthreads();
    if (tid < 128) {
        const int ni = tid >> 6, j = (tid >> 5) & 1, c = tid & 31;
        float s = 0.f;
        #pragma unroll
        for (int w = 0; w < 8; ++w) s += red[((ni * 2 + j) * 8 + w) * 32 + c];
        float* dst = j ? p2 : p1;
        atomicAdd(&dst[(size_t)b * COUT + co0 + ni * 32 + c], s);
    }
}

// ---------------------------------------------------------------------------
// finalize: reduce per-b partials per subject -> scale/shift
// ---------------------------------------------------------------------------
__global__ void finalize_kernel(
    const float* __restrict__ p1, const float* __restrict__ p2,
    const int* __restrict__ subj,
    const float* __restrict__ gamma, const float* __restrict__ beta,
    float* __restrict__ scale, float* __restrict__ shift)
{
    const int idx = blockIdx.x * blockDim.x + threadIdx.x;
    if (idx >= NSUBJ * COUT) return;
    const int s = idx / COUT;
    const int c = idx - s * COUT;
    float s1 = 0.f, s2 = 0.f; int nb = 0;
    for (int b = 0; b < B_; ++b) {
        if (subj[b] == s) {
            s1 += p1[(size_t)b * COUT + c];
            s2 += p2[(size_t)b * COUT + c];
            ++nb;
        }
    }
    const float cnt  = fmaxf((float)nb * (float)T_, 1.0f);
    const float mean = s1 / cnt;
    const float var  = s2 / cnt - mean * mean;
    const float sc = gamma[idx] * (1.0f / sqrtf(var + 1e-5f));
    scale[idx] = sc;
    shift[idx] = beta[idx] - mean * sc;
}

// BN+GELU: y bf16 plain [b][t][c] -> act bf16 halo layout [b][1+t][c]
__global__ __launch_bounds__(256) void bn_gelu_b2b(
    const u16* __restrict__ x, const int* __restrict__ subj,
    const float* __restrict__ scale, const float* __restrict__ shift,
    u16* __restrict__ out)
{
    const u32 base = ((u32)blockIdx.x * 256u + (u32)threadIdx.x) * 8u;
    const u32 b = base / ((u32)T_ * CP);
    const u32 r = base - b * ((u32)T_ * CP);
    const u32 t = r / CP;
    const u32 c = r - t * CP;
    const int s = subj[b];
    const uint4 u = *(const uint4*)(x + base);
    const float* scp = scale + (size_t)s * COUT + c;
    const float* shp = shift + (size_t)s * COUT + c;
    const float4 sca = *(const float4*)(scp);
    const float4 scb = *(const float4*)(scp + 4);
    const float4 sha = *(const float4*)(shp);
    const float4 shb = *(const float4*)(shp + 4);
    const float scv[8] = {sca.x, sca.y, sca.z, sca.w, scb.x, scb.y, scb.z, scb.w};
    const float shv[8] = {sha.x, sha.y, sha.z, sha.w, shb.x, shb.y, shb.z, shb.w};
    const u32 w[4] = {u.x, u.y, u.z, u.w};
    u16 o[8];
    #pragma unroll
    for (int k = 0; k < 4; ++k) {
        const float2 f = bfp2(w[k]);
        o[2 * k]     = f2bf(gelu_exact(f.x * scv[2 * k]     + shv[2 * k]));
        o[2 * k + 1] = f2bf(gelu_exact(f.y * scv[2 * k + 1] + shv[2 * k + 1]));
    }
    u16* op = out + ((size_t)b * TH + 1 + t) * CP + c;
    *(uint4*)op = *(const uint4*)o;
}

// final: BN+GELU + transpose [b][t][c] bf16 plain -> [b][c][t] fp32 (d_out)
__global__ __launch_bounds__(256) void final_tr(
    const u16* __restrict__ x, const int* __restrict__ subj,
    const float* __restrict__ scale, const float* __restrict__ shift,
    float* __restrict__ out)
{
    __shared__ float Lt[64][65];
    const int t0 = blockIdx.x * 64, c0 = blockIdx.y * 64, b = blockIdx.z;
    const int s = subj[b];
    {
        const int tt = threadIdx.x >> 2, chs = (threadIdx.x & 3) * 16;
        const u16* xp = x + ((size_t)b * T_ + t0 + tt) * COUT + c0 + chs;
        const uint4 u0 = *(const uint4*)xp;
        const uint4 u1 = *(const uint4*)(xp + 8);
        const u32 wd[8] = {u0.x, u0.y, u0.z, u0.w, u1.x, u1.y, u1.z, u1.w};
        const float* scp = scale + (size_t)s * COUT + c0 + chs;
        const float* shp = shift + (size_t)s * COUT + c0 + chs;
        #pragma unroll
        for (int k = 0; k < 8; ++k) {
            const float2 f = bfp2(wd[k]);
            Lt[tt][chs + 2 * k]     = gelu_exact(f.x * scp[2 * k]     + shp[2 * k]);
            Lt[tt][chs + 2 * k + 1] = gelu_exact(f.y * scp[2 * k + 1] + shp[2 * k + 1]);
        }
    }
    __syncthreads();
    {
        const int cr = threadIdx.x >> 2, tch = (threadIdx.x & 3) * 16;
        float* op = out + ((size_t)b * COUT + c0 + cr) * T_ + t0 + tch;
        #pragma unroll
        for (int k = 0; k < 16; k += 4)
            *(float4*)(op + k) = make_float4(Lt[tch + k][cr], Lt[tch + k + 1][cr],
                                             Lt[tch + k + 2][cr], Lt[tch + k + 3][cr]);
    }
}

// ---------------------------------------------------------------------------

extern "C" void kernel_launch(void* const* d_in, const int* in_sizes, int n_in,
                              void* d_out, int out_size, void* d_ws, size_t ws_size,
                              hipStream_t stream) {
    const float* X    = (const float*)d_in[0];
    const int*   subj = (const int*)d_in[1];
    const float* w0   = (const float*)d_in[2];
    const float* b0   = (const float*)d_in[3];
    const float* w1   = (const float*)d_in[4];
    const float* b1   = (const float*)d_in[5];
    const float* w2   = (const float*)d_in[6];
    const float* b2   = (const float*)d_in[7];
    const float* g0   = (const float*)d_in[8];
    const float* be0  = (const float*)d_in[9];
    const float* g1   = (const float*)d_in[10];
    const float* be1  = (const float*)d_in[11];
    const float* g2   = (const float*)d_in[12];
    const float* be2  = (const float*)d_in[13];

    // ws layout (identical footprint to previous version)
    const size_t actElems = (size_t)B_ * TH * CP;      // 42,106,880  (84.21 MB)
    const size_t yElems   = (size_t)B_ * T_ * CP;      // 41,943,040  (83.89 MB)
    u16* act  = (u16*)d_ws;
    u16* y    = act + actElems;                        // also absorbs conv stage OOB tail reads
    u16* wb0  = y + yElems;
    u16* wb1  = wb0 + 3 * CP * CP;
    u16* wb2  = wb1 + 3 * CP * CP;
    float* p1 = (float*)(wb2 + 3 * CP * CP);           // [B_][COUT]
    float* p2 = p1 + (size_t)B_ * COUT;                // [B_][COUT]
    float* sc = p2 + (size_t)B_ * COUT;
    float* sh = sc + NSUBJ * COUT;

    const dim3 cgrid(2560);                // conv: 2 t-tiles x 5 co-tiles x 256 b (swizzled 1-D)
    const dim3 pgrid(8, 5, B_);            // prep_x / final_tr tiles
    const int  agrid = (int)(((size_t)B_ * T_ * CP) / 8 / 256);   // 20480
    const int  wgrid = (3 * CP * CP + 255) / 256;                 // 1200
    const int  zgrid = (2 * B_ * COUT) / 4 / 256;                 // 160

    // ---- preparation
    prep_w<<<wgrid, 256, 0, stream>>>(w0, wb0, 271);
    prep_w<<<wgrid, 256, 0, stream>>>(w1, wb1, 320);
    prep_w<<<wgrid, 256, 0, stream>>>(w2, wb2, 320);
    zero_halo<<<80, 256, 0, stream>>>(act);
    prep_x<<<pgrid, 256, 0, stream>>>(X, act);

    // ---- layer 0
    zero_p<<<zgrid, 256, 0, stream>>>((float4*)p1);
    conv_mfma<0><<<cgrid, 256, 0, stream>>>(act, wb0, b0, act, y, p1, p2);
    finalize_kernel<<<5, 256, 0, stream>>>(p1, p2, subj, g0, be0, sc, sh);
    bn_gelu_b2b<<<agrid, 256, 0, stream>>>(y, subj, sc, sh, act);

    // ---- layer 1 (residual)
    zero_p<<<zgrid, 256, 0, stream>>>((float4*)p1);
    conv_mfma<1><<<cgrid, 256, 0, stream>>>(act, wb1, b1, act, y, p1, p2);
    finalize_kernel<<<5, 256, 0, stream>>>(p1, p2, subj, g1, be1, sc, sh);
    bn_gelu_b2b<<<agrid, 256, 0, stream>>>(y, subj, sc, sh, act);

    // ---- layer 2 (residual)
    zero_p<<<zgrid, 256, 0, stream>>>((float4*)p1);
    conv_mfma<1><<<cgrid, 256, 0, stream>>>(act, wb2, b2, act, y, p1, p2);
    finalize_kernel<<<5, 256, 0, stream>>>(p1, p2, subj, g2, be2, sc, sh);
    final_tr<<<pgrid, 256, 0, stream>>>(y, subj, sc, sh, (float*)d_out);
}

// Round 4
// 1261.712 us; speedup vs baseline: 1.4416x; 1.0072x over previous
//
#include <hip/hip_runtime.h>
#include <math.h>

#define B_    256
#define T_    512
#define TH    514          // T + 2 halo rows
#define CP    320          // padded channel stride (both Cin and Cout)
#define COUT  320
#define NSUBJ 4

typedef unsigned int u32;
typedef unsigned short u16;

typedef __bf16 bf16x8 __attribute__((ext_vector_type(8)));
typedef float  f32x16 __attribute__((ext_vector_type(16)));

union FragU { uint4 u4; bf16x8 v; };

__device__ __forceinline__ float bf2f(u16 u) {
    union { u32 i; float f; } v; v.i = ((u32)u) << 16; return v.f;
}
__device__ __forceinline__ u16 f2bf(float f) {
    union { float ff; u32 i; } v; v.ff = f;
    u32 x = v.i;
    x += 0x7fffu + ((x >> 16) & 1u);   // RNE
    return (u16)(x >> 16);
}
__device__ __forceinline__ float2 bfp2(u32 u) {
    float2 r;
    r.x = bf2f((u16)(u & 0xffffu));
    r.y = bf2f((u16)(u >> 16));
    return r;
}
__device__ __forceinline__ float gelu_exact(float x) {
    return 0.5f * x * (1.0f + erff(x * 0.70710678118654752440f));
}
__device__ __forceinline__ bf16x8 ldfrag(const u16* p) {
    FragU f; f.u4 = *(const uint4*)p; return f.v;
}
// async global->LDS, 16B per lane; LDS dest is wave-uniform base + lane*16
__device__ __forceinline__ void gload16(const u16* g, u16* l) {
    __builtin_amdgcn_global_load_lds(
        (const __attribute__((address_space(1))) u32*)(const void*)g,
        (__attribute__((address_space(3))) u32*)(void*)l, 16, 0, 0);
}
// involution on LDS byte offsets: bits 4-6 ^= bits 7-9 (affected < source -> bijective,
// self-inverse). Spreads 8 consecutive 64B rows over all 8 bank-groups.
__device__ __forceinline__ const u16* swz(const char* base, int row, int cb) {
    const int a = row * 64 + cb;
    return (const u16*)(base + (a ^ (((a >> 7) & 7) << 4)));
}

// ---------------------------------------------------------------------------
// prep_w: fp32 [co][Cin][3] -> bf16 [tap][co][CP] (ci >= Cin zeroed)
// ---------------------------------------------------------------------------
__global__ void prep_w(const float* __restrict__ w, u16* __restrict__ wb, int Cin) {
    const int idx = blockIdx.x * 256 + threadIdx.x;
    if (idx >= 3 * CP * CP) return;
    const int tap = idx / (CP * CP);
    const int r   = idx - tap * CP * CP;
    const int co  = r / CP;
    const int ci  = r - co * CP;
    const float v = (ci < Cin) ? w[((size_t)co * Cin + ci) * 3 + tap] : 0.f;
    wb[idx] = f2bf(v);
}

// zero halo rows (t=-1 and t=T) of the act buffer [B][TH][CP]
__global__ void zero_halo(u16* __restrict__ xh) {
    const int idx = blockIdx.x * 256 + threadIdx.x;   // 20480 uint4 total
    const int i8 = idx * 8;
    const int b = i8 / (2 * CP);
    const int r = i8 - b * 2 * CP;
    const int row = (r < CP) ? 0 : (TH - 1);
    const int c   = (r < CP) ? r : r - CP;
    *(uint4*)(xh + ((size_t)b * TH + row) * CP + c) = make_uint4(0u, 0u, 0u, 0u);
}

// zero the BN partial-sum buffers (p1,p2 contiguous: 2*B_*COUT floats)
__global__ void zero_p(float4* __restrict__ p) {
    p[(size_t)blockIdx.x * 256 + threadIdx.x] = make_float4(0.f, 0.f, 0.f, 0.f);
}

// prep_x: X fp32 [b][271][512] -> act bf16 [b][1+t][ci] (ci>=271 zero)
__global__ __launch_bounds__(256) void prep_x(
    const float* __restrict__ X, u16* __restrict__ xh) {
    __shared__ float Lt[64][65];
    const int t0 = blockIdx.x * 64, c0 = blockIdx.y * 64, b = blockIdx.z;
    {
        const int cr = threadIdx.x >> 2, tq = (threadIdx.x & 3) * 16;
        if (c0 + cr < 271) {
            const float* xp = X + ((size_t)b * 271 + c0 + cr) * 512 + t0 + tq;
            #pragma unroll
            for (int k = 0; k < 16; k += 4) {
                const float4 v = *(const float4*)(xp + k);
                Lt[cr][tq + k]     = v.x;
                Lt[cr][tq + k + 1] = v.y;
                Lt[cr][tq + k + 2] = v.z;
                Lt[cr][tq + k + 3] = v.w;
            }
        } else {
            #pragma unroll
            for (int k = 0; k < 16; ++k) Lt[cr][tq + k] = 0.f;
        }
    }
    __syncthreads();
    {
        const int tr = threadIdx.x >> 2, cq = (threadIdx.x & 3) * 16;
        u16 tmp[16];
        #pragma unroll
        for (int k = 0; k < 16; ++k) tmp[k] = f2bf(Lt[cq + k][tr]);
        u16* op = xh + ((size_t)b * TH + 1 + t0 + tr) * CP + c0 + cq;
        *(uint4*)op       = *(const uint4*)&tmp[0];
        *(uint4*)(op + 8) = *(const uint4*)&tmp[8];
    }
}

// ---------------------------------------------------------------------------
// Implicit-GEMM conv1d (K=3 SAME) via mfma_f32_32x32x16_bf16, m97 skeleton.
// 256 thr / 4 waves; block tile M=256 t x N=64 co; wave tile 64 t x 64 co.
// Staging: __builtin_amdgcn_global_load_lds width=16 (no reg round-trip).
// LDS physically linear (gload_lds writes base+lane*16); logical layout is
// rows of 64B. Swizzle applied BOTH sides (rule #21) via involution
// F(a)=a^(((a>>7)&7)<<4): reads use F(logical addr); the per-lane GLOBAL
// source is pre-permuted so physical byte p holds logical F(p).
// Bank check: A/B fragment reads span 32 consecutive rows -> bank-group
// bits {cb4^r1, cb5^r2, r0^r3} hit all 8 groups evenly -> 8 phases = b128
// minimum (conflict-free).
// K-loop: 10 chunks of 32 ci, 2 barriers/chunk; 4 block-contexts/CU overlap.
// Epilogue: bias + residual + BN stats + 2-pass LDS repack -> dwordx4 stores;
// stats atomically added into p1/p2[b][co] (exactly 2 contributors/slot).
// ---------------------------------------------------------------------------
template<int HAS_RES>
__global__ __launch_bounds__(256, 4) void conv_mfma(
    const u16* __restrict__ xh,
    const u16* __restrict__ wb,
    const float* __restrict__ bias,
    const u16* __restrict__ res,     // halo layout [B][TH][CP] (conv input)
    u16* __restrict__ outp,          // bf16 [B][T][CP] pre-BN y
    float* __restrict__ p1,
    float* __restrict__ p2)
{
    __shared__ __attribute__((aligned(16))) u16 Xs[272][32];   // 17,408 B
    __shared__ __attribute__((aligned(16))) u16 Ws[192][32];   // 12,288 B

    const int tid = threadIdx.x;
    // chunked XCD swizzle: 2560 = 8 * 320, bijective
    const u32 bid = blockIdx.x;
    const u32 lin = (bid & 7u) * 320u + (bid >> 3);
    const int b   = (int)(lin / 10u);
    const int r10 = (int)(lin - (u32)b * 10u);
    const int co0 = (r10 >> 1) * 64;
    const int t0  = (r10 & 1) * 256;

    const int lane = tid & 63;
    const int wv   = tid >> 6;       // 0..3, t-subtile = wv*64
    const int l31  = lane & 31;
    const int hi   = lane >> 5;      // 0/1
    const int kb8  = hi * 8;

    f32x16 acc[2][2];
    #pragma unroll
    for (int mi = 0; mi < 2; ++mi)
        #pragma unroll
        for (int ni = 0; ni < 2; ++ni)
            #pragma unroll
            for (int r = 0; r < 16; ++r) acc[mi][ni][r] = 0.f;

    const u16* xbase = xh + ((size_t)b * TH + t0) * CP;   // local row 0 = halo row t0
    const char* XsB = (const char*)&Xs[0][0];
    const char* WsB = (const char*)&Ws[0][0];

    // per-lane source pre-permute matching F: physical p = u*1024 + lane*16
    // holds logical L = F(p):  row_local = (l2^l5) | (l>>3)*2,  octet = (l0^l3)|((l1^l4)<<1)
    const int lrow = (((lane >> 2) ^ (lane >> 5)) & 1) | (((lane >> 3) & 7) << 1);  // 0..15
    const int lq   = ((lane ^ (lane >> 3)) & 1) | ((((lane >> 1) ^ (lane >> 4)) & 1) << 1); // 0..3

    auto stageChunk = [&](int ci0) {
        // 17 X-instrs (rows 0..271, tail clamped to 257) + 12 W-instrs, over 4 waves
        for (int u = wv; u < 29; u += 4) {
            if (u < 17) {
                const int row0 = u * 16 + lrow;           // local halo row
                const int row  = row0 < 258 ? row0 : 257; // clamp junk tail rows
                gload16(xbase + (size_t)row * CP + ci0 + lq * 8, &Xs[u * 16][0]);
            } else {
                const int j = u - 17;                     // 0..11
                const int r = j * 16 + lrow;              // = tap*64 + co_local
                const int tap = r >> 6, col = r & 63;
                gload16(wb + ((size_t)tap * CP + co0 + col) * CP + ci0 + lq * 8,
                        &Ws[j * 16][0]);
            }
        }
    };

    for (int ch = 0; ch < 10; ++ch) {
        stageChunk(ch * 32);
        __syncthreads();               // implies vmcnt(0): staged data visible
        __builtin_amdgcn_s_setprio(1);
        #pragma unroll
        for (int ks = 0; ks < 2; ++ks) {
            const int cb = (ks * 16 + kb8) * 2;           // 0/16/32/48 bytes
            #pragma unroll
            for (int tap = 0; tap < 3; ++tap) {
                const bf16x8 bw0 = ldfrag(swz(WsB, tap * 64 + l31, cb));
                const bf16x8 bw1 = ldfrag(swz(WsB, tap * 64 + 32 + l31, cb));
                #pragma unroll
                for (int mi = 0; mi < 2; ++mi) {
                    const bf16x8 av = ldfrag(swz(XsB, wv * 64 + mi * 32 + l31 + tap, cb));
                    acc[mi][0] = __builtin_amdgcn_mfma_f32_32x32x16_bf16(av, bw0, acc[mi][0], 0, 0, 0);
                    acc[mi][1] = __builtin_amdgcn_mfma_f32_32x32x16_bf16(av, bw1, acc[mi][1], 0, 0, 0);
                }
            }
        }
        __builtin_amdgcn_s_setprio(0);
        __syncthreads();               // readers done before next stage overwrites
    }

    // ---- fused epilogue: bias + residual + BN stats + packed bf16 store
    u16*   oT  = (u16*)&Xs[0][0];      // [128][64] u16 = 16 KB (2 passes over t)
    float* red = (float*)&Ws[0][0];    // [2][2][8][32] floats = 4 KB

    const int wslot = wv * 2 + hi;     // 0..7
    float s1[2] = {0.f, 0.f}, s2[2] = {0.f, 0.f};

    #pragma unroll
    for (int p = 0; p < 2; ++p) {
        if ((wv >> 1) == p) {
            #pragma unroll
            for (int ni = 0; ni < 2; ++ni) {
                const int co = co0 + ni * 32 + l31;
                const float bv = bias[co];
                #pragma unroll
                for (int mi = 0; mi < 2; ++mi) {
                    #pragma unroll
                    for (int r = 0; r < 16; ++r) {
                        const int tl = wv * 64 + mi * 32 + (r & 3) + 8 * (r >> 2) + hi * 4;
                        float v = acc[mi][ni][r] + bv;
                        if (HAS_RES) v += bf2f(res[((size_t)b * TH + t0 + tl + 1) * CP + co]);
                        const u16 h = f2bf(v);
                        const float vq = bf2f(h);   // stats on the rounded stored value
                        s1[ni] += vq;
                        s2[ni] = fmaf(vq, vq, s2[ni]);
                        oT[(tl - p * 128) * 64 + ni * 32 + l31] = h;
                    }
                }
            }
        }
        __syncthreads();
        #pragma unroll
        for (int s = 0; s < 4; ++s) {
            const int i = tid + s * 256;
            const int row = i >> 3, q = i & 7;
            *(uint4*)(outp + ((size_t)b * T_ + t0 + p * 128 + row) * CP + co0 + q * 8) =
                *(const uint4*)&oT[row * 64 + q * 8];
        }
        __syncthreads();
    }

    red[((0 * 2 + 0) * 8 + wslot) * 32 + l31] = s1[0];
    red[((0 * 2 + 1) * 8 + wslot) * 32 + l31] = s2[0];
    red[((1 * 2 + 0) * 8 + wslot) * 32 + l31] = s1[1];
    red[((1 * 2 + 1) * 8 + wslot) * 32 + l31] = s2[1];
    __syncthreads();
    if (tid < 128) {
        const int ni = tid >> 6, j = (tid >> 5) & 1, c = tid & 31;
        float s = 0.f;
        #pragma unroll
        for (int w = 0; w < 8; ++w) s += red[((ni * 2 + j) * 8 + w) * 32 + c];
        float* dst = j ? p2 : p1;
        atomicAdd(&dst[(size_t)b * COUT + co0 + ni * 32 + c], s);
    }
}

// ---------------------------------------------------------------------------
// finalize: reduce per-b partials per subject -> scale/shift
// ---------------------------------------------------------------------------
__global__ void finalize_kernel(
    const float* __restrict__ p1, const float* __restrict__ p2,
    const int* __restrict__ subj,
    const float* __restrict__ gamma, const float* __restrict__ beta,
    float* __restrict__ scale, float* __restrict__ shift)
{
    const int idx = blockIdx.x * blockDim.x + threadIdx.x;
    if (idx >= NSUBJ * COUT) return;
    const int s = idx / COUT;
    const int c = idx - s * COUT;
    float s1 = 0.f, s2 = 0.f; int nb = 0;
    for (int b = 0; b < B_; ++b) {
        if (subj[b] == s) {
            s1 += p1[(size_t)b * COUT + c];
            s2 += p2[(size_t)b * COUT + c];
            ++nb;
        }
    }
    const float cnt  = fmaxf((float)nb * (float)T_, 1.0f);
    const float mean = s1 / cnt;
    const float var  = s2 / cnt - mean * mean;
    const float sc = gamma[idx] * (1.0f / sqrtf(var + 1e-5f));
    scale[idx] = sc;
    shift[idx] = beta[idx] - mean * sc;
}

// BN+GELU: y bf16 plain [b][t][c] -> act bf16 halo layout [b][1+t][c]
__global__ __launch_bounds__(256) void bn_gelu_b2b(
    const u16* __restrict__ x, const int* __restrict__ subj,
    const float* __restrict__ scale, const float* __restrict__ shift,
    u16* __restrict__ out)
{
    const u32 base = ((u32)blockIdx.x * 256u + (u32)threadIdx.x) * 8u;
    const u32 b = base / ((u32)T_ * CP);
    const u32 r = base - b * ((u32)T_ * CP);
    const u32 t = r / CP;
    const u32 c = r - t * CP;
    const int s = subj[b];
    const uint4 u = *(const uint4*)(x + base);
    const float* scp = scale + (size_t)s * COUT + c;
    const float* shp = shift + (size_t)s * COUT + c;
    const float4 sca = *(const float4*)(scp);
    const float4 scb = *(const float4*)(scp + 4);
    const float4 sha = *(const float4*)(shp);
    const float4 shb = *(const float4*)(shp + 4);
    const float scv[8] = {sca.x, sca.y, sca.z, sca.w, scb.x, scb.y, scb.z, scb.w};
    const float shv[8] = {sha.x, sha.y, sha.z, sha.w, shb.x, shb.y, shb.z, shb.w};
    const u32 w[4] = {u.x, u.y, u.z, u.w};
    u16 o[8];
    #pragma unroll
    for (int k = 0; k < 4; ++k) {
        const float2 f = bfp2(w[k]);
        o[2 * k]     = f2bf(gelu_exact(f.x * scv[2 * k]     + shv[2 * k]));
        o[2 * k + 1] = f2bf(gelu_exact(f.y * scv[2 * k + 1] + shv[2 * k + 1]));
    }
    u16* op = out + ((size_t)b * TH + 1 + t) * CP + c;
    *(uint4*)op = *(const uint4*)o;
}

// final: BN+GELU + transpose [b][t][c] bf16 plain -> [b][c][t] fp32 (d_out)
__global__ __launch_bounds__(256) void final_tr(
    const u16* __restrict__ x, const int* __restrict__ subj,
    const float* __restrict__ scale, const float* __restrict__ shift,
    float* __restrict__ out)
{
    __shared__ float Lt[64][65];
    const int t0 = blockIdx.x * 64, c0 = blockIdx.y * 64, b = blockIdx.z;
    const int s = subj[b];
    {
        const int tt = threadIdx.x >> 2, chs = (threadIdx.x & 3) * 16;
        const u16* xp = x + ((size_t)b * T_ + t0 + tt) * COUT + c0 + chs;
        const uint4 u0 = *(const uint4*)xp;
        const uint4 u1 = *(const uint4*)(xp + 8);
        const u32 wd[8] = {u0.x, u0.y, u0.z, u0.w, u1.x, u1.y, u1.z, u1.w};
        const float* scp = scale + (size_t)s * COUT + c0 + chs;
        const float* shp = shift + (size_t)s * COUT + c0 + chs;
        #pragma unroll
        for (int k = 0; k < 8; ++k) {
            const float2 f = bfp2(wd[k]);
            Lt[tt][chs + 2 * k]     = gelu_exact(f.x * scp[2 * k]     + shp[2 * k]);
            Lt[tt][chs + 2 * k + 1] = gelu_exact(f.y * scp[2 * k + 1] + shp[2 * k + 1]);
        }
    }
    __syncthreads();
    {
        const int cr = threadIdx.x >> 2, tch = (threadIdx.x & 3) * 16;
        float* op = out + ((size_t)b * COUT + c0 + cr) * T_ + t0 + tch;
        #pragma unroll
        for (int k = 0; k < 16; k += 4)
            *(float4*)(op + k) = make_float4(Lt[tch + k][cr], Lt[tch + k + 1][cr],
                                             Lt[tch + k + 2][cr], Lt[tch + k + 3][cr]);
    }
}

// ---------------------------------------------------------------------------

extern "C" void kernel_launch(void* const* d_in, const int* in_sizes, int n_in,
                              void* d_out, int out_size, void* d_ws, size_t ws_size,
                              hipStream_t stream) {
    const float* X    = (const float*)d_in[0];
    const int*   subj = (const int*)d_in[1];
    const float* w0   = (const float*)d_in[2];
    const float* b0   = (const float*)d_in[3];
    const float* w1   = (const float*)d_in[4];
    const float* b1   = (const float*)d_in[5];
    const float* w2   = (const float*)d_in[6];
    const float* b2   = (const float*)d_in[7];
    const float* g0   = (const float*)d_in[8];
    const float* be0  = (const float*)d_in[9];
    const float* g1   = (const float*)d_in[10];
    const float* be1  = (const float*)d_in[11];
    const float* g2   = (const float*)d_in[12];
    const float* be2  = (const float*)d_in[13];

    // ws layout (identical footprint to previous version)
    const size_t actElems = (size_t)B_ * TH * CP;      // 42,106,880  (84.21 MB)
    const size_t yElems   = (size_t)B_ * T_ * CP;      // 41,943,040  (83.89 MB)
    u16* act  = (u16*)d_ws;
    u16* y    = act + actElems;
    u16* wb0  = y + yElems;
    u16* wb1  = wb0 + 3 * CP * CP;
    u16* wb2  = wb1 + 3 * CP * CP;
    float* p1 = (float*)(wb2 + 3 * CP * CP);           // [B_][COUT]
    float* p2 = p1 + (size_t)B_ * COUT;                // [B_][COUT]
    float* sc = p2 + (size_t)B_ * COUT;
    float* sh = sc + NSUBJ * COUT;

    const dim3 cgrid(2560);                // conv: 2 t-tiles x 5 co-tiles x 256 b (swizzled 1-D)
    const dim3 pgrid(8, 5, B_);            // prep_x / final_tr tiles
    const int  agrid = (int)(((size_t)B_ * T_ * CP) / 8 / 256);   // 20480
    const int  wgrid = (3 * CP * CP + 255) / 256;                 // 1200
    const int  zgrid = (2 * B_ * COUT) / 4 / 256;                 // 160

    // ---- preparation
    prep_w<<<wgrid, 256, 0, stream>>>(w0, wb0, 271);
    prep_w<<<wgrid, 256, 0, stream>>>(w1, wb1, 320);
    prep_w<<<wgrid, 256, 0, stream>>>(w2, wb2, 320);
    zero_halo<<<80, 256, 0, stream>>>(act);
    prep_x<<<pgrid, 256, 0, stream>>>(X, act);

    // ---- layer 0
    zero_p<<<zgrid, 256, 0, stream>>>((float4*)p1);
    conv_mfma<0><<<cgrid, 256, 0, stream>>>(act, wb0, b0, act, y, p1, p2);
    finalize_kernel<<<5, 256, 0, stream>>>(p1, p2, subj, g0, be0, sc, sh);
    bn_gelu_b2b<<<agrid, 256, 0, stream>>>(y, subj, sc, sh, act);

    // ---- layer 1 (residual)
    zero_p<<<zgrid, 256, 0, stream>>>((float4*)p1);
    conv_mfma<1><<<cgrid, 256, 0, stream>>>(act, wb1, b1, act, y, p1, p2);
    finalize_kernel<<<5, 256, 0, stream>>>(p1, p2, subj, g1, be1, sc, sh);
    bn_gelu_b2b<<<agrid, 256, 0, stream>>>(y, subj, sc, sh, act);

    // ---- layer 2 (residual)
    zero_p<<<zgrid, 256, 0, stream>>>((float4*)p1);
    conv_mfma<1><<<cgrid, 256, 0, stream>>>(act, wb2, b2, act, y, p1, p2);
    finalize_kernel<<<5, 256, 0, stream>>>(p1, p2, subj, g2, be2, sc, sh);
    final_tr<<<pgrid, 256, 0, stream>>>(y, subj, sc, sh, (float*)d_out);
}

// Round 5
// 879.744 us; speedup vs baseline: 2.0676x; 1.4342x over previous
//
#include <hip/hip_runtime.h>
#include <math.h>

#define B_    256
#define T_    512
#define TH    514          // T + 2 halo rows
#define CP    320          // padded channel stride (both Cin and Cout)
#define COUT  320
#define NSUBJ 4

typedef unsigned int u32;
typedef unsigned short u16;

typedef __bf16 bf16x8 __attribute__((ext_vector_type(8)));
typedef float  f32x16 __attribute__((ext_vector_type(16)));

union FragU { uint4 u4; bf16x8 v; };

__device__ __forceinline__ float bf2f(u16 u) {
    union { u32 i; float f; } v; v.i = ((u32)u) << 16; return v.f;
}
__device__ __forceinline__ u16 f2bf(float f) {
    union { float ff; u32 i; } v; v.ff = f;
    u32 x = v.i;
    x += 0x7fffu + ((x >> 16) & 1u);   // RNE
    return (u16)(x >> 16);
}
__device__ __forceinline__ float2 bfp2(u32 u) {
    float2 r;
    r.x = bf2f((u16)(u & 0xffffu));
    r.y = bf2f((u16)(u >> 16));
    return r;
}
__device__ __forceinline__ float gelu_exact(float x) {
    return 0.5f * x * (1.0f + erff(x * 0.70710678118654752440f));
}
__device__ __forceinline__ bf16x8 ldfrag(const u16* p) {
    FragU f; f.u4 = *(const uint4*)p; return f.v;
}
// async global->LDS, 16B per lane; LDS dest is wave-uniform base + lane*16
__device__ __forceinline__ void gload16(const u16* g, u16* l) {
    __builtin_amdgcn_global_load_lds(
        (const __attribute__((address_space(1))) u32*)(const void*)g,
        (__attribute__((address_space(3))) u32*)(void*)l, 16, 0, 0);
}
// involution on tile-relative LDS byte offsets: bits 4-6 ^= bits 7-9
// (affected < source -> bijective, self-inverse). Spreads 8 consecutive
// 64B rows over all 8 bank-groups -> b128 reads over 32 rows conflict-free.
__device__ __forceinline__ const u16* swz(const char* base, int row, int cb) {
    const int a = row * 64 + cb;
    return (const u16*)(base + (a ^ (((a >> 7) & 7) << 4)));
}

// ---------------------------------------------------------------------------
// prep_w: fp32 [co][Cin][3] -> bf16 [tap][co][CP] (ci >= Cin zeroed)
// ---------------------------------------------------------------------------
__global__ void prep_w(const float* __restrict__ w, u16* __restrict__ wb, int Cin) {
    const int idx = blockIdx.x * 256 + threadIdx.x;
    if (idx >= 3 * CP * CP) return;
    const int tap = idx / (CP * CP);
    const int r   = idx - tap * CP * CP;
    const int co  = r / CP;
    const int ci  = r - co * CP;
    const float v = (ci < Cin) ? w[((size_t)co * Cin + ci) * 3 + tap] : 0.f;
    wb[idx] = f2bf(v);
}

// zero halo rows (t=-1 and t=T) of the act buffer [B][TH][CP]
__global__ void zero_halo(u16* __restrict__ xh) {
    const int idx = blockIdx.x * 256 + threadIdx.x;   // 20480 uint4 total
    const int i8 = idx * 8;
    const int b = i8 / (2 * CP);
    const int r = i8 - b * 2 * CP;
    const int row = (r < CP) ? 0 : (TH - 1);
    const int c   = (r < CP) ? r : r - CP;
    *(uint4*)(xh + ((size_t)b * TH + row) * CP + c) = make_uint4(0u, 0u, 0u, 0u);
}

// zero the BN partial-sum buffers (p1,p2 contiguous: 2*B_*COUT floats)
__global__ void zero_p(float4* __restrict__ p) {
    p[(size_t)blockIdx.x * 256 + threadIdx.x] = make_float4(0.f, 0.f, 0.f, 0.f);
}

// prep_x: X fp32 [b][271][512] -> act bf16 [b][1+t][ci] (ci>=271 zero)
__global__ __launch_bounds__(256) void prep_x(
    const float* __restrict__ X, u16* __restrict__ xh) {
    __shared__ float Lt[64][65];
    const int t0 = blockIdx.x * 64, c0 = blockIdx.y * 64, b = blockIdx.z;
    {
        const int cr = threadIdx.x >> 2, tq = (threadIdx.x & 3) * 16;
        if (c0 + cr < 271) {
            const float* xp = X + ((size_t)b * 271 + c0 + cr) * 512 + t0 + tq;
            #pragma unroll
            for (int k = 0; k < 16; k += 4) {
                const float4 v = *(const float4*)(xp + k);
                Lt[cr][tq + k]     = v.x;
                Lt[cr][tq + k + 1] = v.y;
                Lt[cr][tq + k + 2] = v.z;
                Lt[cr][tq + k + 3] = v.w;
            }
        } else {
            #pragma unroll
            for (int k = 0; k < 16; ++k) Lt[cr][tq + k] = 0.f;
        }
    }
    __syncthreads();
    {
        const int tr = threadIdx.x >> 2, cq = (threadIdx.x & 3) * 16;
        u16 tmp[16];
        #pragma unroll
        for (int k = 0; k < 16; ++k) tmp[k] = f2bf(Lt[cq + k][tr]);
        u16* op = xh + ((size_t)b * TH + 1 + t0 + tr) * CP + c0 + cq;
        *(uint4*)op       = *(const uint4*)&tmp[0];
        *(uint4*)(op + 8) = *(const uint4*)&tmp[8];
    }
}

// ---------------------------------------------------------------------------
// Implicit-GEMM conv1d (K=3 SAME) via mfma_f32_32x32x16_bf16.
// 256 thr / 4 waves; block tile M=256 t x N=64 co; wave tile 64 t x 64 co.
// T3-minimum 2-phase pipeline (double-buffered global_load_lds):
//   stage(buf^1, ch+1)  -> issued BEFORE compute
//   compute(buf, ch)    -> ds_read+MFMA hides most of the staged loads' latency
//   __syncthreads()     -> vmcnt(0)+barrier: next buf ready, cur buf free
// One barrier per chunk. LDS 2x29.7KB -> 2 blocks/CU.
// Swizzle (rule #21, both-sides): reads use involution F(a)=a^(((a>>7)&7)<<4)
// on tile-relative offsets; stage pre-permutes the per-lane GLOBAL source so
// physical LDS byte p holds logical F(p) (computed generally from p, so the
// non-aligned tail unit r0=242 is exact).
// Epilogue: bias + residual + BN stats + 2-pass LDS repack -> dwordx4 stores;
// stats atomically added into p1/p2[b][co] (exactly 2 contributors/slot).
// Grid: 2560 blocks, chunked-XCD swizzled (all 10 blocks of one b -> 1 XCD).
// ---------------------------------------------------------------------------
template<int HAS_RES>
__global__ __launch_bounds__(256, 2) void conv_mfma(
    const u16* __restrict__ xh,
    const u16* __restrict__ wb,
    const float* __restrict__ bias,
    const u16* __restrict__ res,     // halo layout [B][TH][CP] (conv input)
    u16* __restrict__ outp,          // bf16 [B][T][CP] pre-BN y
    float* __restrict__ p1,
    float* __restrict__ p2)
{
    __shared__ __attribute__((aligned(1024))) u16 Xs[2][272][32];   // 2 x 17,408 B
    __shared__ __attribute__((aligned(1024))) u16 Ws[2][192][32];   // 2 x 12,288 B

    const int tid = threadIdx.x;
    // chunked XCD swizzle: 2560 = 8 * 320, bijective
    const u32 bid = blockIdx.x;
    const u32 lin = (bid & 7u) * 320u + (bid >> 3);
    const int b   = (int)(lin / 10u);
    const int r10 = (int)(lin - (u32)b * 10u);
    const int co0 = (r10 >> 1) * 64;
    const int t0  = (r10 & 1) * 256;

    const int lane = tid & 63;
    const int wv   = tid >> 6;       // 0..3, t-subtile = wv*64
    const int l31  = lane & 31;
    const int hi   = lane >> 5;      // 0/1
    const int kb8  = hi * 8;

    f32x16 acc[2][2];
    #pragma unroll
    for (int mi = 0; mi < 2; ++mi)
        #pragma unroll
        for (int ni = 0; ni < 2; ++ni)
            #pragma unroll
            for (int r = 0; r < 16; ++r) acc[mi][ni][r] = 0.f;

    const u16* xbase = xh + ((size_t)b * TH + t0) * CP;   // local row 0 = halo row t0

    // stage: physical byte p = r0*64 + lane*16 within the tile must hold the
    // value the swizzled read expects at logical L = F(p).
    auto stageX = [&](int buf, int r0, int ci0) {
        const int p = r0 * 64 + lane * 16;
        const int L = p ^ (((p >> 7) & 7) << 4);
        const int row = L >> 6;            // logical tile row (0..257)
        const int oct = (L >> 4) & 3;      // 8-ci octet within the 32-ci slice
        gload16(xbase + (size_t)row * CP + ci0 + oct * 8, &Xs[buf][r0][0]);
    };
    auto stageW = [&](int buf, int r0, int ci0) {
        const int p = r0 * 64 + lane * 16;
        const int L = p ^ (((p >> 7) & 7) << 4);
        const int row = L >> 6;            // = tap*64 + co_local
        const int oct = (L >> 4) & 3;
        const int tap = row >> 6, col = row & 63;
        gload16(wb + ((size_t)tap * CP + co0 + col) * CP + ci0 + oct * 8,
                &Ws[buf][r0][0]);
    };
    auto stageChunk = [&](int buf, int ci0) {
        // 17 X units (16 aligned + tail at r0=242 covering rows 242..257)
        // + 12 W units, round-robin over the 4 waves
        for (int u = wv; u < 29; u += 4) {
            if (u < 17) stageX(buf, u < 16 ? u * 16 : 242, ci0);
            else        stageW(buf, (u - 17) * 16, ci0);
        }
    };
    auto compute = [&](int buf) {
        const char* XsB = (const char*)&Xs[buf][0][0];
        const char* WsB = (const char*)&Ws[buf][0][0];
        #pragma unroll
        for (int ks = 0; ks < 2; ++ks) {
            const int cb = (ks * 16 + kb8) * 2;           // 0/16/32/48 bytes
            #pragma unroll
            for (int tap = 0; tap < 3; ++tap) {
                const bf16x8 bw0 = ldfrag(swz(WsB, tap * 64 + l31, cb));
                const bf16x8 bw1 = ldfrag(swz(WsB, tap * 64 + 32 + l31, cb));
                #pragma unroll
                for (int mi = 0; mi < 2; ++mi) {
                    const bf16x8 av = ldfrag(swz(XsB, wv * 64 + mi * 32 + l31 + tap, cb));
                    acc[mi][0] = __builtin_amdgcn_mfma_f32_32x32x16_bf16(av, bw0, acc[mi][0], 0, 0, 0);
                    acc[mi][1] = __builtin_amdgcn_mfma_f32_32x32x16_bf16(av, bw1, acc[mi][1], 0, 0, 0);
                }
            }
        }
    };

    // ---- 2-phase pipelined K-loop: one barrier per chunk
    stageChunk(0, 0);
    __syncthreads();                       // drain stage 0
    for (int ch = 0; ch < 10; ++ch) {
        const int cur = ch & 1;
        if (ch < 9) stageChunk(cur ^ 1, (ch + 1) * 32);   // issue next BEFORE compute
        __builtin_amdgcn_s_setprio(1);
        compute(cur);
        __builtin_amdgcn_s_setprio(0);
        __syncthreads();                   // vmcnt(0): next buf staged; cur buf free
    }

    // ---- fused epilogue: bias + residual + BN stats + packed bf16 store
    u16*   oT  = (u16*)&Xs[0][0][0];   // [128][64] u16 = 16 KB (2 passes over t)
    float* red = (float*)&Ws[0][0][0]; // [2][2][8][32] floats = 4 KB

    const int wslot = wv * 2 + hi;     // 0..7
    float s1[2] = {0.f, 0.f}, s2[2] = {0.f, 0.f};

    #pragma unroll
    for (int p = 0; p < 2; ++p) {
        if ((wv >> 1) == p) {
            #pragma unroll
            for (int ni = 0; ni < 2; ++ni) {
                const int co = co0 + ni * 32 + l31;
                const float bv = bias[co];
                #pragma unroll
                for (int mi = 0; mi < 2; ++mi) {
                    #pragma unroll
                    for (int r = 0; r < 16; ++r) {
                        const int tl = wv * 64 + mi * 32 + (r & 3) + 8 * (r >> 2) + hi * 4;
                        float v = acc[mi][ni][r] + bv;
                        if (HAS_RES) v += bf2f(res[((size_t)b * TH + t0 + tl + 1) * CP + co]);
                        const u16 h = f2bf(v);
                        const float vq = bf2f(h);   // stats on the rounded stored value
                        s1[ni] += vq;
                        s2[ni] = fmaf(vq, vq, s2[ni]);
                        oT[(tl - p * 128) * 64 + ni * 32 + l31] = h;
                    }
                }
            }
        }
        __syncthreads();
        #pragma unroll
        for (int s = 0; s < 4; ++s) {
            const int i = tid + s * 256;
            const int row = i >> 3, q = i & 7;
            *(uint4*)(outp + ((size_t)b * T_ + t0 + p * 128 + row) * CP + co0 + q * 8) =
                *(const uint4*)&oT[row * 64 + q * 8];
        }
        __syncthreads();
    }

    red[((0 * 2 + 0) * 8 + wslot) * 32 + l31] = s1[0];
    red[((0 * 2 + 1) * 8 + wslot) * 32 + l31] = s2[0];
    red[((1 * 2 + 0) * 8 + wslot) * 32 + l31] = s1[1];
    red[((1 * 2 + 1) * 8 + wslot) * 32 + l31] = s2[1];
    __syncthreads();
    if (tid < 128) {
        const int ni = tid >> 6, j = (tid >> 5) & 1, c = tid & 31;
        float s = 0.f;
        #pragma unroll
        for (int w = 0; w < 8; ++w) s += red[((ni * 2 + j) * 8 + w) * 32 + c];
        float* dst = j ? p2 : p1;
        atomicAdd(&dst[(size_t)b * COUT + co0 + ni * 32 + c], s);
    }
}

// ---------------------------------------------------------------------------
// finalize: reduce per-b partials per subject -> scale/shift
// ---------------------------------------------------------------------------
__global__ void finalize_kernel(
    const float* __restrict__ p1, const float* __restrict__ p2,
    const int* __restrict__ subj,
    const float* __restrict__ gamma, const float* __restrict__ beta,
    float* __restrict__ scale, float* __restrict__ shift)
{
    const int idx = blockIdx.x * blockDim.x + threadIdx.x;
    if (idx >= NSUBJ * COUT) return;
    const int s = idx / COUT;
    const int c = idx - s * COUT;
    float s1 = 0.f, s2 = 0.f; int nb = 0;
    for (int b = 0; b < B_; ++b) {
        if (subj[b] == s) {
            s1 += p1[(size_t)b * COUT + c];
            s2 += p2[(size_t)b * COUT + c];
            ++nb;
        }
    }
    const float cnt  = fmaxf((float)nb * (float)T_, 1.0f);
    const float mean = s1 / cnt;
    const float var  = s2 / cnt - mean * mean;
    const float sc = gamma[idx] * (1.0f / sqrtf(var + 1e-5f));
    scale[idx] = sc;
    shift[idx] = beta[idx] - mean * sc;
}

// BN+GELU: y bf16 plain [b][t][c] -> act bf16 halo layout [b][1+t][c]
__global__ __launch_bounds__(256) void bn_gelu_b2b(
    const u16* __restrict__ x, const int* __restrict__ subj,
    const float* __restrict__ scale, const float* __restrict__ shift,
    u16* __restrict__ out)
{
    const u32 base = ((u32)blockIdx.x * 256u + (u32)threadIdx.x) * 8u;
    const u32 b = base / ((u32)T_ * CP);
    const u32 r = base - b * ((u32)T_ * CP);
    const u32 t = r / CP;
    const u32 c = r - t * CP;
    const int s = subj[b];
    const uint4 u = *(const uint4*)(x + base);
    const float* scp = scale + (size_t)s * COUT + c;
    const float* shp = shift + (size_t)s * COUT + c;
    const float4 sca = *(const float4*)(scp);
    const float4 scb = *(const float4*)(scp + 4);
    const float4 sha = *(const float4*)(shp);
    const float4 shb = *(const float4*)(shp + 4);
    const float scv[8] = {sca.x, sca.y, sca.z, sca.w, scb.x, scb.y, scb.z, scb.w};
    const float shv[8] = {sha.x, sha.y, sha.z, sha.w, shb.x, shb.y, shb.z, shb.w};
    const u32 w[4] = {u.x, u.y, u.z, u.w};
    u16 o[8];
    #pragma unroll
    for (int k = 0; k < 4; ++k) {
        const float2 f = bfp2(w[k]);
        o[2 * k]     = f2bf(gelu_exact(f.x * scv[2 * k]     + shv[2 * k]));
        o[2 * k + 1] = f2bf(gelu_exact(f.y * scv[2 * k + 1] + shv[2 * k + 1]));
    }
    u16* op = out + ((size_t)b * TH + 1 + t) * CP + c;
    *(uint4*)op = *(const uint4*)o;
}

// final: BN+GELU + transpose [b][t][c] bf16 plain -> [b][c][t] fp32 (d_out)
__global__ __launch_bounds__(256) void final_tr(
    const u16* __restrict__ x, const int* __restrict__ subj,
    const float* __restrict__ scale, const float* __restrict__ shift,
    float* __restrict__ out)
{
    __shared__ float Lt[64][65];
    const int t0 = blockIdx.x * 64, c0 = blockIdx.y * 64, b = blockIdx.z;
    const int s = subj[b];
    {
        const int tt = threadIdx.x >> 2, chs = (threadIdx.x & 3) * 16;
        const u16* xp = x + ((size_t)b * T_ + t0 + tt) * COUT + c0 + chs;
        const uint4 u0 = *(const uint4*)xp;
        const uint4 u1 = *(const uint4*)(xp + 8);
        const u32 wd[8] = {u0.x, u0.y, u0.z, u0.w, u1.x, u1.y, u1.z, u1.w};
        const float* scp = scale + (size_t)s * COUT + c0 + chs;
        const float* shp = shift + (size_t)s * COUT + c0 + chs;
        #pragma unroll
        for (int k = 0; k < 8; ++k) {
            const float2 f = bfp2(wd[k]);
            Lt[tt][chs + 2 * k]     = gelu_exact(f.x * scp[2 * k]     + shp[2 * k]);
            Lt[tt][chs + 2 * k + 1] = gelu_exact(f.y * scp[2 * k + 1] + shp[2 * k + 1]);
        }
    }
    __syncthreads();
    {
        const int cr = threadIdx.x >> 2, tch = (threadIdx.x & 3) * 16;
        float* op = out + ((size_t)b * COUT + c0 + cr) * T_ + t0 + tch;
        #pragma unroll
        for (int k = 0; k < 16; k += 4)
            *(float4*)(op + k) = make_float4(Lt[tch + k][cr], Lt[tch + k + 1][cr],
                                             Lt[tch + k + 2][cr], Lt[tch + k + 3][cr]);
    }
}

// ---------------------------------------------------------------------------

extern "C" void kernel_launch(void* const* d_in, const int* in_sizes, int n_in,
                              void* d_out, int out_size, void* d_ws, size_t ws_size,
                              hipStream_t stream) {
    const float* X    = (const float*)d_in[0];
    const int*   subj = (const int*)d_in[1];
    const float* w0   = (const float*)d_in[2];
    const float* b0   = (const float*)d_in[3];
    const float* w1   = (const float*)d_in[4];
    const float* b1   = (const float*)d_in[5];
    const float* w2   = (const float*)d_in[6];
    const float* b2   = (const float*)d_in[7];
    const float* g0   = (const float*)d_in[8];
    const float* be0  = (const float*)d_in[9];
    const float* g1   = (const float*)d_in[10];
    const float* be1  = (const float*)d_in[11];
    const float* g2   = (const float*)d_in[12];
    const float* be2  = (const float*)d_in[13];

    // ws layout (identical footprint to previous version)
    const size_t actElems = (size_t)B_ * TH * CP;      // 42,106,880  (84.21 MB)
    const size_t yElems   = (size_t)B_ * T_ * CP;      // 41,943,040  (83.89 MB)
    u16* act  = (u16*)d_ws;
    u16* y    = act + actElems;
    u16* wb0  = y + yElems;
    u16* wb1  = wb0 + 3 * CP * CP;
    u16* wb2  = wb1 + 3 * CP * CP;
    float* p1 = (float*)(wb2 + 3 * CP * CP);           // [B_][COUT]
    float* p2 = p1 + (size_t)B_ * COUT;                // [B_][COUT]
    float* sc = p2 + (size_t)B_ * COUT;
    float* sh = sc + NSUBJ * COUT;

    const dim3 cgrid(2560);                // conv: 2 t-tiles x 5 co-tiles x 256 b (swizzled 1-D)
    const dim3 pgrid(8, 5, B_);            // prep_x / final_tr tiles
    const int  agrid = (int)(((size_t)B_ * T_ * CP) / 8 / 256);   // 20480
    const int  wgrid = (3 * CP * CP + 255) / 256;                 // 1200
    const int  zgrid = (2 * B_ * COUT) / 4 / 256;                 // 160

    // ---- preparation
    prep_w<<<wgrid, 256, 0, stream>>>(w0, wb0, 271);
    prep_w<<<wgrid, 256, 0, stream>>>(w1, wb1, 320);
    prep_w<<<wgrid, 256, 0, stream>>>(w2, wb2, 320);
    zero_halo<<<80, 256, 0, stream>>>(act);
    prep_x<<<pgrid, 256, 0, stream>>>(X, act);

    // ---- layer 0
    zero_p<<<zgrid, 256, 0, stream>>>((float4*)p1);
    conv_mfma<0><<<cgrid, 256, 0, stream>>>(act, wb0, b0, act, y, p1, p2);
    finalize_kernel<<<5, 256, 0, stream>>>(p1, p2, subj, g0, be0, sc, sh);
    bn_gelu_b2b<<<agrid, 256, 0, stream>>>(y, subj, sc, sh, act);

    // ---- layer 1 (residual)
    zero_p<<<zgrid, 256, 0, stream>>>((float4*)p1);
    conv_mfma<1><<<cgrid, 256, 0, stream>>>(act, wb1, b1, act, y, p1, p2);
    finalize_kernel<<<5, 256, 0, stream>>>(p1, p2, subj, g1, be1, sc, sh);
    bn_gelu_b2b<<<agrid, 256, 0, stream>>>(y, subj, sc, sh, act);

    // ---- layer 2 (residual)
    zero_p<<<zgrid, 256, 0, stream>>>((float4*)p1);
    conv_mfma<1><<<cgrid, 256, 0, stream>>>(act, wb2, b2, act, y, p1, p2);
    finalize_kernel<<<5, 256, 0, stream>>>(p1, p2, subj, g2, be2, sc, sh);
    final_tr<<<pgrid, 256, 0, stream>>>(y, subj, sc, sh, (float*)d_out);
}

// Round 7
// 842.574 us; speedup vs baseline: 2.1588x; 1.0441x over previous
//
#include <hip/hip_runtime.h>
#include <math.h>

#define B_    256
#define T_    512
#define TH    514          // T + 2 halo rows
#define CP    320          // padded channel stride (both Cin and Cout)
#define COUT  320
#define NSUBJ 4

typedef unsigned int u32;
typedef unsigned short u16;

typedef __bf16 bf16x8 __attribute__((ext_vector_type(8)));
typedef float  f32x16 __attribute__((ext_vector_type(16)));

union FragU { uint4 u4; bf16x8 v; };

__device__ __forceinline__ float bf2f(u16 u) {
    union { u32 i; float f; } v; v.i = ((u32)u) << 16; return v.f;
}
__device__ __forceinline__ u16 f2bf(float f) {
    union { float ff; u32 i; } v; v.ff = f;
    u32 x = v.i;
    x += 0x7fffu + ((x >> 16) & 1u);   // RNE
    return (u16)(x >> 16);
}
__device__ __forceinline__ float2 bfp2(u32 u) {
    float2 r;
    r.x = bf2f((u16)(u & 0xffffu));
    r.y = bf2f((u16)(u >> 16));
    return r;
}
__device__ __forceinline__ float gelu_exact(float x) {
    return 0.5f * x * (1.0f + erff(x * 0.70710678118654752440f));
}
__device__ __forceinline__ bf16x8 ldfrag(const u16* p) {
    FragU f; f.u4 = *(const uint4*)p; return f.v;
}
// async global->LDS, 16B per lane; LDS dest is wave-uniform base + lane*16
__device__ __forceinline__ void gload16(const u16* g, u16* l) {
    __builtin_amdgcn_global_load_lds(
        (const __attribute__((address_space(1))) u32*)(const void*)g,
        (__attribute__((address_space(3))) u32*)(void*)l, 16, 0, 0);
}
// involution on tile-relative LDS byte offsets: bits 4-5 ^= bits 7-8.
// Bank-quad bits of the read addr become (cb4^r1, cb5^r2, r0) -- a bijection
// of (row mod 8) for ANY row alignment -> tap-shifted A-fragment reads are
// conflict-free too (the R4/R5 variant used r0^r3 in b6, which collided for
// misaligned 8-row windows: rows r and r+8 shared a quad).
__device__ __forceinline__ const u16* swz(const char* base, int row, int cb) {
    const int a = row * 64 + cb;
    return (const u16*)(base + (a ^ (((a >> 7) & 3) << 4)));
}

// ---------------------------------------------------------------------------
// prep_w_all: fp32 {w0,w1,w2}[co][Cin][3] -> bf16 wb[3 layers][tap][co][CP]
// (ci >= Cin zeroed; the three wb buffers are contiguous in ws)
// ---------------------------------------------------------------------------
__global__ void prep_w_all(const float* __restrict__ w0,
                           const float* __restrict__ w1,
                           const float* __restrict__ w2,
                           u16* __restrict__ wb) {
    const int idx = blockIdx.x * 256 + threadIdx.x;
    if (idx >= 9 * CP * CP) return;
    const int which = idx / (3 * CP * CP);
    const int rem   = idx - which * 3 * CP * CP;
    const int tap = rem / (CP * CP);
    const int r   = rem - tap * CP * CP;
    const int co  = r / CP;
    const int ci  = r - co * CP;
    const float* w = which == 0 ? w0 : (which == 1 ? w1 : w2);
    const int Cin  = which == 0 ? 271 : 320;
    const float v = (ci < Cin) ? w[((size_t)co * Cin + ci) * 3 + tap] : 0.f;
    wb[idx] = f2bf(v);
}

// zero halo rows (t=-1 and t=T) of the act buffer [B][TH][CP]
__global__ void zero_halo(u16* __restrict__ xh) {
    const int idx = blockIdx.x * 256 + threadIdx.x;   // 20480 uint4 total
    const int i8 = idx * 8;
    const int b = i8 / (2 * CP);
    const int r = i8 - b * 2 * CP;
    const int row = (r < CP) ? 0 : (TH - 1);
    const int c   = (r < CP) ? r : r - CP;
    *(uint4*)(xh + ((size_t)b * TH + row) * CP + c) = make_uint4(0u, 0u, 0u, 0u);
}

// zero the BN partial-sum buffers (p1,p2 contiguous: 2*B_*COUT floats)
__global__ void zero_p(float4* __restrict__ p) {
    p[(size_t)blockIdx.x * 256 + threadIdx.x] = make_float4(0.f, 0.f, 0.f, 0.f);
}

// prep_x: X fp32 [b][271][512] -> act bf16 [b][1+t][ci] (ci>=271 zero)
__global__ __launch_bounds__(256) void prep_x(
    const float* __restrict__ X, u16* __restrict__ xh) {
    __shared__ float Lt[64][65];
    const int t0 = blockIdx.x * 64, c0 = blockIdx.y * 64, b = blockIdx.z;
    {
        const int cr = threadIdx.x >> 2, tq = (threadIdx.x & 3) * 16;
        if (c0 + cr < 271) {
            const float* xp = X + ((size_t)b * 271 + c0 + cr) * 512 + t0 + tq;
            #pragma unroll
            for (int k = 0; k < 16; k += 4) {
                const float4 v = *(const float4*)(xp + k);
                Lt[cr][tq + k]     = v.x;
                Lt[cr][tq + k + 1] = v.y;
                Lt[cr][tq + k + 2] = v.z;
                Lt[cr][tq + k + 3] = v.w;
            }
        } else {
            #pragma unroll
            for (int k = 0; k < 16; ++k) Lt[cr][tq + k] = 0.f;
        }
    }
    __syncthreads();
    {
        const int tr = threadIdx.x >> 2, cq = (threadIdx.x & 3) * 16;
        u16 tmp[16];
        #pragma unroll
        for (int k = 0; k < 16; ++k) tmp[k] = f2bf(Lt[cq + k][tr]);
        u16* op = xh + ((size_t)b * TH + 1 + t0 + tr) * CP + c0 + cq;
        *(uint4*)op       = *(const uint4*)&tmp[0];
        *(uint4*)(op + 8) = *(const uint4*)&tmp[8];
    }
}

// ---------------------------------------------------------------------------
// Implicit-GEMM conv1d (K=3 SAME) via mfma_f32_32x32x16_bf16.
// 256 thr / 4 waves; block tile M=256 t x N=64 co; wave tile 64 t x 64 co.
// T3-minimum 2-phase pipeline (double-buffered global_load_lds):
//   stage(buf^1, ch+1) -> compute(buf, ch) -> __syncthreads (vmcnt drain
//   lands AFTER the MFMA section). One barrier per chunk; 2 blocks/CU.
// Swizzle (rule #21, both-sides): involution F(a)=a^(((a>>7)&3)<<4) on
// tile-relative offsets; stage pre-permutes the per-lane GLOBAL source so
// physical LDS byte p holds logical F(p). Conflict-free for aligned W-reads
// AND tap-shifted A-reads (see swz comment).
// Epilogue: bias + residual + BN stats + 2-pass LDS repack -> dwordx4 stores;
// stats atomically added into p1/p2[b][co] (exactly 2 contributors/slot).
// Grid: 2560 blocks, chunked-XCD swizzled (all 10 blocks of one b -> 1 XCD).
// ---------------------------------------------------------------------------
template<int HAS_RES>
__global__ __launch_bounds__(256, 2) void conv_mfma(
    const u16* __restrict__ xh,
    const u16* __restrict__ wb,
    const float* __restrict__ bias,
    const u16* __restrict__ res,     // halo layout [B][TH][CP] (conv input)
    u16* __restrict__ outp,          // bf16 [B][T][CP] pre-BN y
    float* __restrict__ p1,
    float* __restrict__ p2)
{
    __shared__ __attribute__((aligned(1024))) u16 Xs[2][272][32];   // 2 x 17,408 B
    __shared__ __attribute__((aligned(1024))) u16 Ws[2][192][32];   // 2 x 12,288 B

    const int tid = threadIdx.x;
    // chunked XCD swizzle: 2560 = 8 * 320, bijective
    const u32 bid = blockIdx.x;
    const u32 lin = (bid & 7u) * 320u + (bid >> 3);
    const int b   = (int)(lin / 10u);
    const int r10 = (int)(lin - (u32)b * 10u);
    const int co0 = (r10 >> 1) * 64;
    const int t0  = (r10 & 1) * 256;

    const int lane = tid & 63;
    const int wv   = tid >> 6;       // 0..3, t-subtile = wv*64
    const int l31  = lane & 31;
    const int hi   = lane >> 5;      // 0/1
    const int kb8  = hi * 8;

    f32x16 acc[2][2];
    #pragma unroll
    for (int mi = 0; mi < 2; ++mi)
        #pragma unroll
        for (int ni = 0; ni < 2; ++ni)
            #pragma unroll
            for (int r = 0; r < 16; ++r) acc[mi][ni][r] = 0.f;

    const u16* xbase = xh + ((size_t)b * TH + t0) * CP;   // local row 0 = halo row t0

    // stage: physical byte p = r0*64 + lane*16 within the tile must hold the
    // value the swizzled read expects at logical L = F(p). F only touches
    // bits 4-5, so the logical row equals the physical row; only the 8-ci
    // octet is permuted per lane.
    auto stageX = [&](int buf, int r0, int ci0) {
        const int p = r0 * 64 + lane * 16;
        const int L = p ^ (((p >> 7) & 3) << 4);
        const int row = L >> 6;            // logical tile row (0..257)
        const int oct = (L >> 4) & 3;      // 8-ci octet within the 32-ci slice
        gload16(xbase + (size_t)row * CP + ci0 + oct * 8, &Xs[buf][r0][0]);
    };
    auto stageW = [&](int buf, int r0, int ci0) {
        const int p = r0 * 64 + lane * 16;
        const int L = p ^ (((p >> 7) & 3) << 4);
        const int row = L >> 6;            // = tap*64 + co_local
        const int oct = (L >> 4) & 3;
        const int tap = row >> 6, col = row & 63;
        gload16(wb + ((size_t)tap * CP + co0 + col) * CP + ci0 + oct * 8,
                &Ws[buf][r0][0]);
    };
    auto stageChunk = [&](int buf, int ci0) {
        // 17 X units (16 aligned + tail at r0=242 covering rows 242..257)
        // + 12 W units, round-robin over the 4 waves
        for (int u = wv; u < 29; u += 4) {
            if (u < 17) stageX(buf, u < 16 ? u * 16 : 242, ci0);
            else        stageW(buf, (u - 17) * 16, ci0);
        }
    };
    auto compute = [&](int buf) {
        const char* XsB = (const char*)&Xs[buf][0][0];
        const char* WsB = (const char*)&Ws[buf][0][0];
        #pragma unroll
        for (int ks = 0; ks < 2; ++ks) {
            const int cb = (ks * 16 + kb8) * 2;           // 0/16/32/48 bytes
            #pragma unroll
            for (int tap = 0; tap < 3; ++tap) {
                const bf16x8 bw0 = ldfrag(swz(WsB, tap * 64 + l31, cb));
                const bf16x8 bw1 = ldfrag(swz(WsB, tap * 64 + 32 + l31, cb));
                #pragma unroll
                for (int mi = 0; mi < 2; ++mi) {
                    const bf16x8 av = ldfrag(swz(XsB, wv * 64 + mi * 32 + l31 + tap, cb));
                    acc[mi][0] = __builtin_amdgcn_mfma_f32_32x32x16_bf16(av, bw0, acc[mi][0], 0, 0, 0);
                    acc[mi][1] = __builtin_amdgcn_mfma_f32_32x32x16_bf16(av, bw1, acc[mi][1], 0, 0, 0);
                }
            }
        }
    };

    // ---- 2-phase pipelined K-loop: one barrier per chunk
    stageChunk(0, 0);
    __syncthreads();                       // drain stage 0
    for (int ch = 0; ch < 10; ++ch) {
        const int cur = ch & 1;
        if (ch < 9) stageChunk(cur ^ 1, (ch + 1) * 32);   // issue next BEFORE compute
        __builtin_amdgcn_s_setprio(1);
        compute(cur);
        __builtin_amdgcn_s_setprio(0);
        __syncthreads();                   // vmcnt(0): next buf staged; cur buf free
    }

    // ---- fused epilogue: bias + residual + BN stats + packed bf16 store
    u16*   oT  = (u16*)&Xs[0][0][0];   // [128][64] u16 = 16 KB (2 passes over t)
    float* red = (float*)&Ws[0][0][0]; // [2][2][8][32] floats = 4 KB

    const int wslot = wv * 2 + hi;     // 0..7
    float s1[2] = {0.f, 0.f}, s2[2] = {0.f, 0.f};

    #pragma unroll
    for (int p = 0; p < 2; ++p) {
        if ((wv >> 1) == p) {
            #pragma unroll
            for (int ni = 0; ni < 2; ++ni) {
                const int co = co0 + ni * 32 + l31;
                const float bv = bias[co];
                #pragma unroll
                for (int mi = 0; mi < 2; ++mi) {
                    #pragma unroll
                    for (int r = 0; r < 16; ++r) {
                        const int tl = wv * 64 + mi * 32 + (r & 3) + 8 * (r >> 2) + hi * 4;
                        float v = acc[mi][ni][r] + bv;
                        if (HAS_RES) v += bf2f(res[((size_t)b * TH + t0 + tl + 1) * CP + co]);
                        const u16 h = f2bf(v);
                        const float vq = bf2f(h);   // stats on the rounded stored value
                        s1[ni] += vq;
                        s2[ni] = fmaf(vq, vq, s2[ni]);
                        oT[(tl - p * 128) * 64 + ni * 32 + l31] = h;
                    }
                }
            }
        }
        __syncthreads();
        #pragma unroll
        for (int s = 0; s < 4; ++s) {
            const int i = tid + s * 256;
            const int row = i >> 3, q = i & 7;
            *(uint4*)(outp + ((size_t)b * T_ + t0 + p * 128 + row) * CP + co0 + q * 8) =
                *(const uint4*)&oT[row * 64 + q * 8];
        }
        __syncthreads();
    }

    red[((0 * 2 + 0) * 8 + wslot) * 32 + l31] = s1[0];
    red[((0 * 2 + 1) * 8 + wslot) * 32 + l31] = s2[0];
    red[((1 * 2 + 0) * 8 + wslot) * 32 + l31] = s1[1];
    red[((1 * 2 + 1) * 8 + wslot) * 32 + l31] = s2[1];
    __syncthreads();
    if (tid < 128) {
        const int ni = tid >> 6, j = (tid >> 5) & 1, c = tid & 31;
        float s = 0.f;
        #pragma unroll
        for (int w = 0; w < 8; ++w) s += red[((ni * 2 + j) * 8 + w) * 32 + c];
        float* dst = j ? p2 : p1;
        atomicAdd(&dst[(size_t)b * COUT + co0 + ni * 32 + c], s);
    }
}

// ---------------------------------------------------------------------------
// finalize: reduce per-b partials per subject -> scale/shift.
// grid 20 x 256: block = (subject s, 64-channel tile); wave q sums b-range
// [q*64, q*64+64); LDS reduce across the 4 waves.
// ---------------------------------------------------------------------------
__global__ __launch_bounds__(256) void finalize_kernel(
    const float* __restrict__ p1, const float* __restrict__ p2,
    const int* __restrict__ subj,
    const float* __restrict__ gamma, const float* __restrict__ beta,
    float* __restrict__ scale, float* __restrict__ shift)
{
    __shared__ float r1[4][64], r2[4][64], rc[4][64];
    const int s  = blockIdx.x / 5;
    const int c0 = (blockIdx.x - s * 5) * 64;
    const int q  = threadIdx.x >> 6;
    const int cl = threadIdx.x & 63;
    const int c  = c0 + cl;
    float s1 = 0.f, s2 = 0.f; float nb = 0.f;
    for (int bb = 0; bb < 64; ++bb) {
        const int b = q * 64 + bb;
        if (subj[b] == s) {
            s1 += p1[(size_t)b * COUT + c];
            s2 += p2[(size_t)b * COUT + c];
            nb += 1.f;
        }
    }
    r1[q][cl] = s1; r2[q][cl] = s2; rc[q][cl] = nb;
    __syncthreads();
    if (threadIdx.x < 64) {
        const float t1 = r1[0][cl] + r1[1][cl] + r1[2][cl] + r1[3][cl];
        const float t2 = r2[0][cl] + r2[1][cl] + r2[2][cl] + r2[3][cl];
        const float cnt = fmaxf((rc[0][cl] + rc[1][cl] + rc[2][cl] + rc[3][cl]) * (float)T_, 1.0f);
        const int idx = s * COUT + c;
        const float mean = t1 / cnt;
        const float var  = t2 / cnt - mean * mean;
        const float sc = gamma[idx] * (1.0f / sqrtf(var + 1e-5f));
        scale[idx] = sc;
        shift[idx] = beta[idx] - mean * sc;
    }
}

// BN+GELU: y bf16 plain [b][t][c] -> act bf16 halo layout [b][1+t][c]
__global__ __launch_bounds__(256) void bn_gelu_b2b(
    const u16* __restrict__ x, const int* __restrict__ subj,
    const float* __restrict__ scale, const float* __restrict__ shift,
    u16* __restrict__ out)
{
    const u32 base = ((u32)blockIdx.x * 256u + (u32)threadIdx.x) * 8u;
    const u32 b = base / ((u32)T_ * CP);
    const u32 r = base - b * ((u32)T_ * CP);
    const u32 t = r / CP;
    const u32 c = r - t * CP;
    const int s = subj[b];
    const uint4 u = *(const uint4*)(x + base);
    const float* scp = scale + (size_t)s * COUT + c;
    const float* shp = shift + (size_t)s * COUT + c;
    const float4 sca = *(const float4*)(scp);
    const float4 scb = *(const float4*)(scp + 4);
    const float4 sha = *(const float4*)(shp);
    const float4 shb = *(const float4*)(shp + 4);
    const float scv[8] = {sca.x, sca.y, sca.z, sca.w, scb.x, scb.y, scb.z, scb.w};
    const float shv[8] = {sha.x, sha.y, sha.z, sha.w, shb.x, shb.y, shb.z, shb.w};
    const u32 w[4] = {u.x, u.y, u.z, u.w};
    u16 o[8];
    #pragma unroll
    for (int k = 0; k < 4; ++k) {
        const float2 f = bfp2(w[k]);
        o[2 * k]     = f2bf(gelu_exact(f.x * scv[2 * k]     + shv[2 * k]));
        o[2 * k + 1] = f2bf(gelu_exact(f.y * scv[2 * k + 1] + shv[2 * k + 1]));
    }
    u16* op = out + ((size_t)b * TH + 1 + t) * CP + c;
    *(uint4*)op = *(const uint4*)o;
}

// final: BN+GELU + transpose [b][t][c] bf16 plain -> [b][c][t] fp32 (d_out)
__global__ __launch_bounds__(256) void final_tr(
    const u16* __restrict__ x, const int* __restrict__ subj,
    const float* __restrict__ scale, const float* __restrict__ shift,
    float* __restrict__ out)
{
    __shared__ float Lt[64][65];
    const int t0 = blockIdx.x * 64, c0 = blockIdx.y * 64, b = blockIdx.z;
    const int s = subj[b];
    {
        const int tt = threadIdx.x >> 2, chs = (threadIdx.x & 3) * 16;
        const u16* xp = x + ((size_t)b * T_ + t0 + tt) * COUT + c0 + chs;
        const uint4 u0 = *(const uint4*)xp;
        const uint4 u1 = *(const uint4*)(xp + 8);
        const u32 wd[8] = {u0.x, u0.y, u0.z, u0.w, u1.x, u1.y, u1.z, u1.w};
        const float* scp = scale + (size_t)s * COUT + c0 + chs;
        const float* shp = shift + (size_t)s * COUT + c0 + chs;
        #pragma unroll
        for (int k = 0; k < 8; ++k) {
            const float2 f = bfp2(wd[k]);
            Lt[tt][chs + 2 * k]     = gelu_exact(f.x * scp[2 * k]     + shp[2 * k]);
            Lt[tt][chs + 2 * k + 1] = gelu_exact(f.y * scp[2 * k + 1] + shp[2 * k + 1]);
        }
    }
    __syncthreads();
    {
        const int cr = threadIdx.x >> 2, tch = (threadIdx.x & 3) * 16;
        float* op = out + ((size_t)b * COUT + c0 + cr) * T_ + t0 + tch;
        #pragma unroll
        for (int k = 0; k < 16; k += 4)
            *(float4*)(op + k) = make_float4(Lt[tch + k][cr], Lt[tch + k + 1][cr],
                                             Lt[tch + k + 2][cr], Lt[tch + k + 3][cr]);
    }
}

// ---------------------------------------------------------------------------

extern "C" void kernel_launch(void* const* d_in, const int* in_sizes, int n_in,
                              void* d_out, int out_size, void* d_ws, size_t ws_size,
                              hipStream_t stream) {
    const float* X    = (const float*)d_in[0];
    const int*   subj = (const int*)d_in[1];
    const float* w0   = (const float*)d_in[2];
    const float* b0   = (const float*)d_in[3];
    const float* w1   = (const float*)d_in[4];
    const float* b1   = (const float*)d_in[5];
    const float* w2   = (const float*)d_in[6];
    const float* b2   = (const float*)d_in[7];
    const float* g0   = (const float*)d_in[8];
    const float* be0  = (const float*)d_in[9];
    const float* g1   = (const float*)d_in[10];
    const float* be1  = (const float*)d_in[11];
    const float* g2   = (const float*)d_in[12];
    const float* be2  = (const float*)d_in[13];

    // ws layout (identical footprint to previous version)
    const size_t actElems = (size_t)B_ * TH * CP;      // 42,106,880  (84.21 MB)
    const size_t yElems   = (size_t)B_ * T_ * CP;      // 41,943,040  (83.89 MB)
    u16* act  = (u16*)d_ws;
    u16* y    = act + actElems;
    u16* wb0  = y + yElems;
    u16* wb1  = wb0 + 3 * CP * CP;
    u16* wb2  = wb1 + 3 * CP * CP;
    float* p1 = (float*)(wb2 + 3 * CP * CP);           // [B_][COUT]
    float* p2 = p1 + (size_t)B_ * COUT;                // [B_][COUT]
    float* sc = p2 + (size_t)B_ * COUT;
    float* sh = sc + NSUBJ * COUT;

    const dim3 cgrid(2560);                // conv: 2 t-tiles x 5 co-tiles x 256 b (swizzled 1-D)
    const dim3 pgrid(8, 5, B_);            // prep_x / final_tr tiles
    const int  agrid = (int)(((size_t)B_ * T_ * CP) / 8 / 256);   // 20480
    const int  wgrid = (9 * CP * CP + 255) / 256;                 // 3600
    const int  zgrid = (2 * B_ * COUT) / 4 / 256;                 // 160

    // ---- preparation
    prep_w_all<<<wgrid, 256, 0, stream>>>(w0, w1, w2, wb0);
    zero_halo<<<80, 256, 0, stream>>>(act);
    prep_x<<<pgrid, 256, 0, stream>>>(X, act);

    // ---- layer 0
    zero_p<<<zgrid, 256, 0, stream>>>((float4*)p1);
    conv_mfma<0><<<cgrid, 256, 0, stream>>>(act, wb0, b0, act, y, p1, p2);
    finalize_kernel<<<20, 256, 0, stream>>>(p1, p2, subj, g0, be0, sc, sh);
    bn_gelu_b2b<<<agrid, 256, 0, stream>>>(y, subj, sc, sh, act);

    // ---- layer 1 (residual)
    zero_p<<<zgrid, 256, 0, stream>>>((float4*)p1);
    conv_mfma<1><<<cgrid, 256, 0, stream>>>(act, wb1, b1, act, y, p1, p2);
    finalize_kernel<<<20, 256, 0, stream>>>(p1, p2, subj, g1, be1, sc, sh);
    bn_gelu_b2b<<<agrid, 256, 0, stream>>>(y, subj, sc, sh, act);

    // ---- layer 2 (residual, bf16 out)
    zero_p<<<zgrid, 256, 0, stream>>>((float4*)p1);
    conv_mfma<1><<<cgrid, 256, 0, stream>>>(act, wb2, b2, act, y, p1, p2);
    finalize_kernel<<<20, 256, 0, stream>>>(p1, p2, subj, g2, be2, sc, sh);
    final_tr<<<pgrid, 256, 0, stream>>>(y, subj, sc, sh, (float*)d_out);
}